// Round 1
// baseline (166.772 us; speedup 1.0000x reference)
//
#include <hip/hip_runtime.h>
#include <hip/hip_bf16.h>
#include <cstddef>
#include <cstdint>

#define Bb 4
#define Tt 1024
#define Dd 1024
#define Hh 16

typedef __bf16 bf16x8 __attribute__((ext_vector_type(8)));
typedef __bf16 bf16x4 __attribute__((ext_vector_type(4)));
typedef float  f32x4  __attribute__((ext_vector_type(4)));

__device__ __forceinline__ void gload16(const void* g, void* l) {
    __builtin_amdgcn_global_load_lds(
        (const __attribute__((address_space(1))) void*)g,
        (__attribute__((address_space(3))) void*)l, 16, 0, 0);
}

// ---------------------------------------------------------------------------
// Fused prep: [0,4096) cast x -> bf16; [4096,4864) Wqkv transpose;
// [4864,5120) Wproj transpose.  (unchanged)
// ---------------------------------------------------------------------------
__global__ __launch_bounds__(256) void prep(const float* __restrict__ x,
                                            const float* __restrict__ Wqkv,
                                            const float* __restrict__ Wproj,
                                            __bf16* __restrict__ xb,
                                            __bf16* __restrict__ wqT,
                                            __bf16* __restrict__ wpT) {
    const int bid = blockIdx.x;
    if (bid < 4096) {  // cast
        int i = bid * 256 + threadIdx.x;
        float4 v = ((const float4*)x)[i];
        bf16x4 o = { (__bf16)v.x, (__bf16)v.y, (__bf16)v.z, (__bf16)v.w };
        ((bf16x4*)xb)[i] = o;
        return;
    }
    __shared__ float ld[64][65];
    const float* in;
    __bf16* out;
    int K, N, k0, n0;
    if (bid < 4096 + 768) {
        int j = bid - 4096;
        in = Wqkv; out = wqT; K = 1024; N = 3072;
        k0 = (j & 15) * 64; n0 = (j >> 4) * 64;
    } else {
        int j = bid - 4096 - 768;
        in = Wproj; out = wpT; K = 1024; N = 1024;
        k0 = (j & 15) * 64; n0 = (j >> 4) * 64;
    }
    #pragma unroll
    for (int i = 0; i < 16; i++) {
        int idx = i * 256 + threadIdx.x;
        int r = idx >> 6, c = idx & 63;
        ld[r][c] = in[(size_t)(k0 + r) * N + n0 + c];
    }
    __syncthreads();
    #pragma unroll
    for (int i = 0; i < 16; i++) {
        int idx = i * 256 + threadIdx.x;
        int r = idx >> 6, c = idx & 63;
        out[(size_t)(n0 + r) * K + k0 + c] = (__bf16)ld[c][r];
    }
}

// ---------------------------------------------------------------------------
// QKV GEMM, NEW: 256x256 tile, BK=64, 8 waves (2Mx4N), 512 threads,
// 128 KiB LDS double-buffer, 8-phase schedule (4 phases / K-tile) with
// counted vmcnt(6) (never 0 in main loop) + raw s_barrier + setprio around
// MFMA clusters.  Stage order per tile t: P0:Ah1(t+1) P1:Bh0(t+2)
// P2:Bh1(t+2) P3:Ah0(t+2); region-retirement proof:
//   B region of buf[t&1] fully ds_read in P0 (all 8 B frags) -> overwritten
//   only by DMA issued in P1/P2 (after P0's trailing barrier).
//   A region read in P0 (rows +0..63) and P2 (+64..127) -> overwritten only
//   by DMA issued in P3.  Each phase's ds_reads are consumed by that
//   phase's MFMAs before its trailing barrier, so no wave's pending LDS
//   read can collide with a later-issued DMA.
// vmcnt(6): 2 loads/half-tile x 3 half-tiles in flight -> at the end-of-tile
// wait exactly the next tile's 8 loads are forced complete.
// Epilogue: per-128-row slice through LDS (stride 264) -> coalesced bf16x8
// Cout stores; V blocks (col0>=2048) also emit vt[b][h][d][t].
// Q columns (<1024) pre-scaled by 0.125.
// ---------------------------------------------------------------------------
__device__ __forceinline__ void stage_half(const __bf16* __restrict__ g,
                                           __bf16* l, int tid) {
    #pragma unroll
    for (int s = 0; s < 2; ++s) {
        const int c = s * 512 + tid;      // 0..1023 chunk within half-tile
        const int r = c >> 3;             // row 0..127
        const int seg = (c & 7) ^ (r & 7);
        gload16(&g[(size_t)r * 1024 + seg * 8], &l[c * 8]);
    }
}

template <int MH>
__device__ __forceinline__ void load_af(bf16x8 (&af)[4][2], const __bf16* AsC,
                                        int wy, int l15, int quad) {
    #pragma unroll
    for (int mi = 0; mi < 4; ++mi)
        #pragma unroll
        for (int kc = 0; kc < 2; ++kc)
            af[mi][kc] = *(const bf16x8*)&AsC[(wy * 128 + MH * 64 + mi * 16 + l15) * 64 +
                                              (((kc * 4 + quad) ^ (l15 & 7)) * 8)];
}

template <int MH, int NH>
__device__ __forceinline__ void mfma_quad(f32x4 (&acc)[8][4], const bf16x8 (&af)[4][2],
                                          const bf16x8 (&bf)[4][2]) {
    #pragma unroll
    for (int mi = 0; mi < 4; ++mi)
        #pragma unroll
        for (int nj = 0; nj < 2; ++nj) {
            f32x4 c = acc[MH * 4 + mi][NH * 2 + nj];
            c = __builtin_amdgcn_mfma_f32_16x16x32_bf16(af[mi][0], bf[NH * 2 + nj][0], c, 0, 0, 0);
            c = __builtin_amdgcn_mfma_f32_16x16x32_bf16(af[mi][1], bf[NH * 2 + nj][1], c, 0, 0, 0);
            acc[MH * 4 + mi][NH * 2 + nj] = c;
        }
}

__global__ __launch_bounds__(512, 2) void gemm_qkv(const __bf16* __restrict__ A,
                                                   const __bf16* __restrict__ Bt,
                                                   const float* __restrict__ bias,
                                                   __bf16* __restrict__ Cout,
                                                   __bf16* __restrict__ vt) {
    constexpr int N = 3072;
    constexpr int NT = 16;                   // K=1024 / BK=64
    __shared__ __align__(16) __bf16 smem[65536];   // 128 KiB: As[2][16384] | Bs[2][16384]

    const int tid  = threadIdx.x;
    const int lane = tid & 63;
    const int wave = tid >> 6;
    const int wy = wave >> 2, wx = wave & 3;       // 2 x 4 waves
    const int l15 = lane & 15, quad = lane >> 4;
    const size_t row0 = (size_t)blockIdx.y * 256;
    const size_t col0 = (size_t)blockIdx.x * 256;

    const __bf16* const Ab  = A  + row0 * 1024;
    const __bf16* const Bb_ = Bt + col0 * 1024;

    f32x4 acc[8][4] = {};
    bf16x8 af[4][2], bf[4][2];

    // ---- prologue: tile0 (4 halves) + Bh0(1),Bh1(1),Ah0(1) = 14 loads ----
    stage_half(Ab, smem, tid);                                    // Ah0(0)
    stage_half(Ab + (size_t)128 * 1024, smem + 8192, tid);        // Ah1(0)
    stage_half(Bb_, smem + 32768, tid);                           // Bh0(0)
    stage_half(Bb_ + (size_t)128 * 1024, smem + 32768 + 8192, tid);  // Bh1(0)
    stage_half(Bb_ + 64, smem + 32768 + 16384, tid);              // Bh0(1)
    stage_half(Bb_ + (size_t)128 * 1024 + 64, smem + 32768 + 16384 + 8192, tid); // Bh1(1)
    stage_half(Ab + 64, smem + 16384, tid);                       // Ah0(1)
    asm volatile("s_waitcnt vmcnt(6)" ::: "memory");              // tile0 landed
    __builtin_amdgcn_s_barrier();

    for (int t = 0; t < NT; ++t) {
        const int cur = t & 1;
        __bf16* const AsC = smem + cur * 16384;
        __bf16* const BsC = smem + 32768 + cur * 16384;
        __bf16* const AsN = smem + (cur ^ 1) * 16384;

        // ---------------- phase 0 ----------------
        load_af<0>(af, AsC, wy, l15, quad);
        #pragma unroll
        for (int nj = 0; nj < 4; ++nj)
            #pragma unroll
            for (int kc = 0; kc < 2; ++kc)
                bf[nj][kc] = *(const bf16x8*)&BsC[(wx * 64 + nj * 16 + l15) * 64 +
                                                  (((kc * 4 + quad) ^ (l15 & 7)) * 8)];
        if (t + 1 < NT) stage_half(Ab + (size_t)128 * 1024 + (t + 1) * 64, AsN + 8192, tid);
        __builtin_amdgcn_s_barrier();
        asm volatile("s_waitcnt lgkmcnt(0)" ::: "memory");
        __builtin_amdgcn_s_setprio(1);
        mfma_quad<0, 0>(acc, af, bf);
        __builtin_amdgcn_s_setprio(0);
        __builtin_amdgcn_s_barrier();

        // ---------------- phase 1 ----------------
        if (t + 2 < NT) stage_half(Bb_ + (t + 2) * 64, BsC, tid);
        __builtin_amdgcn_s_barrier();
        asm volatile("s_waitcnt lgkmcnt(0)" ::: "memory");
        __builtin_amdgcn_s_setprio(1);
        mfma_quad<0, 1>(acc, af, bf);
        __builtin_amdgcn_s_setprio(0);
        __builtin_amdgcn_s_barrier();

        // ---------------- phase 2 ----------------
        load_af<1>(af, AsC, wy, l15, quad);
        if (t + 2 < NT) stage_half(Bb_ + (size_t)128 * 1024 + (t + 2) * 64, BsC + 8192, tid);
        __builtin_amdgcn_s_barrier();
        asm volatile("s_waitcnt lgkmcnt(0)" ::: "memory");
        __builtin_amdgcn_s_setprio(1);
        mfma_quad<1, 0>(acc, af, bf);
        __builtin_amdgcn_s_setprio(0);
        __builtin_amdgcn_s_barrier();

        // ---------------- phase 3 ----------------
        if (t + 2 < NT) stage_half(Ab + (t + 2) * 64, AsC, tid);
        if (t + 2 < NT) {
            asm volatile("s_waitcnt vmcnt(6)" ::: "memory");   // next tile's 8 loads done
        } else if (t + 1 < NT) {
            asm volatile("s_waitcnt vmcnt(0)" ::: "memory");   // drain: no t+2 prefetch exists
        }
        __builtin_amdgcn_s_barrier();
        asm volatile("s_waitcnt lgkmcnt(0)" ::: "memory");
        __builtin_amdgcn_s_setprio(1);
        mfma_quad<1, 1>(acc, af, bf);
        __builtin_amdgcn_s_setprio(0);
        __builtin_amdgcn_s_barrier();
    }

    // ---- epilogue: two 128-row slices through LDS (stride 264) ----
    const float scale = (col0 < 1024) ? 0.125f : 1.0f;
    const int isV = (col0 >= 2048);
    for (int sl = 0; sl < 2; ++sl) {
        if (wy == sl) {
            #pragma unroll
            for (int nj = 0; nj < 4; ++nj) {
                const int cl = wx * 64 + nj * 16 + l15;
                const float bj = bias[col0 + cl];
                #pragma unroll
                for (int mi = 0; mi < 8; ++mi) {
                    #pragma unroll
                    for (int r = 0; r < 4; ++r)
                        smem[(mi * 16 + quad * 4 + r) * 264 + cl] =
                            (__bf16)((acc[mi][nj][r] + bj) * scale);
                }
            }
        }
        __syncthreads();
        #pragma unroll
        for (int p = 0; p < 8; ++p) {
            const int idx = p * 512 + tid;       // 0..4095
            const int row = idx >> 5, ch = idx & 31;
            bf16x8 v = *(const bf16x8*)&smem[row * 264 + ch * 8];
            *(bf16x8*)&Cout[(row0 + sl * 128 + row) * N + col0 + ch * 8] = v;
        }
        if (isV) {  // V block: also write vt[b][h][d][t]
            const int bidx = (int)(row0 >> 10);
            const int t0g  = (int)(row0 & 1023) + sl * 128;
            const int cl   = tid & 255;          // tile column 0..255
            const int th   = tid >> 8;           // 0..1
            const int hd   = (int)(col0 - 2048) + cl;
            const size_t vrow = ((size_t)((bidx * Hh + (hd >> 6)) * 64 + (hd & 63))) * Tt + t0g;
            #pragma unroll
            for (int p = 0; p < 8; ++p) {
                const int tch = th * 8 + p;      // 0..15 (x8 rows)
                bf16x8 v;
                #pragma unroll
                for (int u = 0; u < 8; ++u) v[u] = smem[(tch * 8 + u) * 264 + cl];
                *(bf16x8*)&vt[vrow + tch * 8] = v;
            }
        }
        __syncthreads();
    }
}

// ---------------------------------------------------------------------------
// 128x64-tile GEMM (proj), BK=64, single-buffered.  (unchanged)
// ---------------------------------------------------------------------------
__global__ __launch_bounds__(256) void gemm_bf16_n64(const __bf16* __restrict__ A,
                                                     const __bf16* __restrict__ Bt,
                                                     const float* __restrict__ bias,
                                                     float* __restrict__ Cout,
                                                     int M, int N, int K) {
    __shared__ __align__(16) __bf16 As[128 * 64];
    __shared__ __align__(16) __bf16 Bs[64 * 64];
    const int tid  = threadIdx.x;
    const int lane = tid & 63;
    const int wave = tid >> 6;
    const int wy = wave >> 1, wx = wave & 1;
    const int l15 = lane & 15, quad = lane >> 4;
    const size_t row0 = (size_t)blockIdx.y * 128;
    const size_t col0 = (size_t)blockIdx.x * 64;

    f32x4 acc[4][2] = {};

    for (int k0 = 0; k0 < K; k0 += 64) {
        #pragma unroll
        for (int i = 0; i < 4; i++) {
            int c = i * 256 + tid;
            int r = c >> 3, seg = (c & 7) ^ (r & 7);
            gload16(&A[(row0 + r) * K + k0 + seg * 8], &As[c * 8]);
        }
        #pragma unroll
        for (int i = 0; i < 2; i++) {
            int c = i * 256 + tid;
            int r = c >> 3, seg = (c & 7) ^ (r & 7);
            gload16(&Bt[(col0 + r) * K + k0 + seg * 8], &Bs[c * 8]);
        }
        __syncthreads();
        #pragma unroll
        for (int kc = 0; kc < 2; kc++) {
            bf16x8 af[4], bfr[2];
            #pragma unroll
            for (int i = 0; i < 4; i++)
                af[i] = *(const bf16x8*)&As[(wy * 64 + i * 16 + l15) * 64 +
                                            (((kc * 4 + quad) ^ (l15 & 7)) * 8)];
            #pragma unroll
            for (int j = 0; j < 2; j++)
                bfr[j] = *(const bf16x8*)&Bs[(wx * 32 + j * 16 + l15) * 64 +
                                             (((kc * 4 + quad) ^ (l15 & 7)) * 8)];
            #pragma unroll
            for (int i = 0; i < 4; i++)
                #pragma unroll
                for (int j = 0; j < 2; j++)
                    acc[i][j] = __builtin_amdgcn_mfma_f32_16x16x32_bf16(af[i], bfr[j], acc[i][j], 0, 0, 0);
        }
        __syncthreads();
    }

    #pragma unroll
    for (int j = 0; j < 2; j++) {
        const size_t col = col0 + wx * 32 + j * 16 + l15;
        const float bj = bias[col];
        #pragma unroll
        for (int i = 0; i < 4; i++) {
            const size_t row = row0 + wy * 64 + i * 16 + quad * 4;
            #pragma unroll
            for (int r = 0; r < 4; r++)
                Cout[(row + r) * N + col] = acc[i][j][r] + bj;
        }
    }
}

// ---------------------------------------------------------------------------
// Flash attention (S^T = K @ Q^T).  (unchanged)
// ---------------------------------------------------------------------------
__global__ __launch_bounds__(256, 4) void attn_mfma(const __bf16* __restrict__ qkv,
                                                    const __bf16* __restrict__ vt,
                                                    const int* __restrict__ mask,
                                                    __bf16* __restrict__ att) {
    __shared__ __align__(16) __bf16 Ks[2][4096];
    __shared__ __align__(16) __bf16 Vs[2][4096];
    __shared__ __align__(16) __bf16 Ps[4][1024];

    const int h  = blockIdx.x & 15;
    const int b  = blockIdx.x >> 4;
    const int qt = 15 - blockIdx.y;  // LPT: longest blocks dispatch first
    const int tid = threadIdx.x, lane = tid & 63, wave = tid >> 6;
    const int l15 = lane & 15, quad = lane >> 4;

    // stage Q (swizzled) through Ks[0]
    #pragma unroll
    for (int i = 0; i < 2; i++) {
        int c = i * 256 + tid;
        int rr = c >> 3, ch = c & 7;
        gload16(&qkv[((size_t)(b * Tt + qt * 64 + rr)) * 3072 + h * 64 + ((ch ^ (rr & 7)) * 8)],
                &Ks[0][c * 8]);
    }

    // mask ballot pass: tile p's 64 bits end up in lane-group (lane&15)==p
    uint32_t mlo = 0, mhi = 0;
    for (int p = 0; p < 16; p++) {
        unsigned long long bal = __ballot(mask[b * Tt + p * 64 + lane] != 0);
        if ((lane & 15) == p) { mlo = (uint32_t)bal; mhi = (uint32_t)(bal >> 32); }
    }

    __syncthreads();
    bf16x8 qf0 = *(const bf16x8*)&Ks[0][(wave * 16 + l15) * 64 + ((quad ^ (l15 & 7)) * 8)];
    bf16x8 qf1 = *(const bf16x8*)&Ks[0][(wave * 16 + l15) * 64 + (((4 + quad) ^ (l15 & 7)) * 8)];
    __syncthreads();  // Q frag reads done -> Ks[0] reusable

    #pragma unroll
    for (int i = 0; i < 2; i++) {
        int c = i * 256 + tid;
        int rr = c >> 3, ch = c & 7, sw = ((ch ^ (rr & 7)) * 8);
        gload16(&qkv[((size_t)(b * Tt + rr)) * 3072 + 1024 + h * 64 + sw], &Ks[0][c * 8]);
        gload16(&vt[((size_t)((b * Hh + h) * 64 + rr)) * Tt + sw], &Vs[0][c * 8]);
    }

    f32x4 Oacc[4] = {};
    float lsum = 0.0f;

    for (int kt = 0; kt <= qt; kt++) {
        __syncthreads();  // DMA(kt) complete (issued a full compute phase ago)
        const int cur = kt & 1;
        if (kt < qt) {
            #pragma unroll
            for (int i = 0; i < 2; i++) {
                int c = i * 256 + tid;
                int rr = c >> 3, ch = c & 7, sw = ((ch ^ (rr & 7)) * 8);
                gload16(&qkv[((size_t)(b * Tt + (kt + 1) * 64 + rr)) * 3072 + 1024 + h * 64 + sw],
                        &Ks[cur ^ 1][c * 8]);
                gload16(&vt[((size_t)((b * Hh + h) * 64 + rr)) * Tt + (kt + 1) * 64 + sw],
                        &Vs[cur ^ 1][c * 8]);
            }
        }

        // mask bits for this tile (uniform readlane, no memory access)
        const uint32_t lo = (uint32_t)__builtin_amdgcn_readlane((int)mlo, kt);
        const uint32_t hi = (uint32_t)__builtin_amdgcn_readlane((int)mhi, kt);

        bf16x8 ak[4][2];
        #pragma unroll
        for (int j = 0; j < 4; j++)
            #pragma unroll
            for (int kc = 0; kc < 2; kc++)
                ak[j][kc] = *(const bf16x8*)&Ks[cur][(j * 16 + l15) * 64 +
                                                     (((kc * 4 + quad) ^ (l15 & 7)) * 8)];
        #pragma unroll
        for (int j = 0; j < 4; j++) {
            f32x4 st = {};
            st = __builtin_amdgcn_mfma_f32_16x16x32_bf16(ak[j][0], qf0, st, 0, 0, 0);
            st = __builtin_amdgcn_mfma_f32_16x16x32_bf16(ak[j][1], qf1, st, 0, 0, 0);
            const uint32_t fld = (j < 2) ? (lo >> (j * 16)) : (hi >> ((j - 2) * 16));
            bf16x4 pv;
            #pragma unroll
            for (int r = 0; r < 4; r++) {
                const int tloc = j * 16 + quad * 4 + r;
                bool keep = (fld >> (quad * 4 + r)) & 1;
                if (kt == qt) keep = keep && (tloc <= wave * 16 + l15);
                const float pe = keep ? __expf(st[r]) : 0.0f;
                lsum += pe;
                pv[r] = (__bf16)pe;
            }
            *(bf16x4*)&Ps[wave][l15 * 64 + (((j * 4 + quad) ^ ((l15 & 7) << 1)) * 4)] = pv;
        }

        bf16x8 av[4][2];
        #pragma unroll
        for (int n = 0; n < 4; n++)
            #pragma unroll
            for (int kc = 0; kc < 2; kc++)
                av[n][kc] = *(const bf16x8*)&Vs[cur][(n * 16 + l15) * 64 +
                                                     (((kc * 4 + quad) ^ (l15 & 7)) * 8)];
        bf16x8 p0 = *(const bf16x8*)&Ps[wave][l15 * 64 + (((2 * quad) ^ ((l15 & 7) << 1)) * 4)];
        bf16x8 p1 = *(const bf16x8*)&Ps[wave][l15 * 64 + (((2 * (4 + quad)) ^ ((l15 & 7) << 1)) * 4)];
        #pragma unroll
        for (int n = 0; n < 4; n++) {
            Oacc[n] = __builtin_amdgcn_mfma_f32_16x16x32_bf16(av[n][0], p0, Oacc[n], 0, 0, 0);
            Oacc[n] = __builtin_amdgcn_mfma_f32_16x16x32_bf16(av[n][1], p1, Oacc[n], 0, 0, 0);
        }
    }

    float lt = lsum;
    lt += __shfl_xor(lt, 16);
    lt += __shfl_xor(lt, 32);
    const float inv = 1.0f / lt;
    const int q = qt * 64 + wave * 16 + l15;
    #pragma unroll
    for (int n = 0; n < 4; n++) {
        bf16x4 o;
        #pragma unroll
        for (int r = 0; r < 4; r++) o[r] = (__bf16)(Oacc[n][r] * inv);
        *(bf16x4*)&att[((size_t)(b * Tt + q)) * Dd + h * 64 + n * 16 + quad * 4] = o;
    }
}

// ---------------------------------------------------------------------------
extern "C" void kernel_launch(void* const* d_in, const int* in_sizes, int n_in,
                              void* d_out, int out_size, void* d_ws, size_t ws_size,
                              hipStream_t stream) {
    const float* x     = (const float*)d_in[0];
    const float* Wqkv  = (const float*)d_in[1];
    const float* bqkv  = (const float*)d_in[2];
    const float* Wproj = (const float*)d_in[3];
    const float* bproj = (const float*)d_in[4];
    const int*   mask  = (const int*)d_in[5];
    float* out = (float*)d_out;

    __bf16* xb  = (__bf16*)d_ws;                         // 4096*1024
    __bf16* wqT = xb  + (size_t)4096 * 1024;             // 3072*1024
    __bf16* wpT = wqT + (size_t)3072 * 1024;             // 1024*1024
    __bf16* qkv = wpT + (size_t)1024 * 1024;             // 4096*3072
    __bf16* vt  = qkv + (size_t)4096 * 3072;             // 4*16*64*1024
    __bf16* att = vt  + (size_t)4 * 16 * 64 * 1024;      // 4096*1024

    prep<<<4096 + 768 + 256, 256, 0, stream>>>(x, Wqkv, Wproj, xb, wqT, wpT);

    gemm_qkv<<<dim3(12, 16), 512, 0, stream>>>(xb, wqT, bqkv, qkv, vt);

    attn_mfma<<<dim3(64, 16), 256, 0, stream>>>(qkv, vt, mask, att);

    gemm_bf16_n64<<<dim3(16, 32), 256, 0, stream>>>(att, wpT, bproj, out, 4096, 1024, 1024);
}

// Round 2
// 165.289 us; speedup vs baseline: 1.0090x; 1.0090x over previous
//
#include <hip/hip_runtime.h>
#include <hip/hip_bf16.h>
#include <cstddef>
#include <cstdint>

#define Bb 4
#define Tt 1024
#define Dd 1024
#define Hh 16

typedef __bf16 bf16x8 __attribute__((ext_vector_type(8)));
typedef __bf16 bf16x4 __attribute__((ext_vector_type(4)));
typedef float  f32x4  __attribute__((ext_vector_type(4)));

__device__ __forceinline__ void gload16(const void* g, void* l) {
    __builtin_amdgcn_global_load_lds(
        (const __attribute__((address_space(1))) void*)g,
        (__attribute__((address_space(3))) void*)l, 16, 0, 0);
}

#define LGKM4() asm volatile("s_waitcnt lgkmcnt(4)" ::: "memory")
#define LGKM8() asm volatile("s_waitcnt lgkmcnt(8)" ::: "memory")
#define LGKM0() asm volatile("s_waitcnt lgkmcnt(0)" ::: "memory")
#define VMC6()  asm volatile("s_waitcnt vmcnt(6)" ::: "memory")
#define VMC0()  asm volatile("s_waitcnt vmcnt(0)" ::: "memory")
#define SB()    __builtin_amdgcn_s_barrier()
#define SCB()   __builtin_amdgcn_sched_barrier(0)

// ---------------------------------------------------------------------------
// Fused prep: [0,4096) cast x -> bf16; [4096,4864) Wqkv transpose;
// [4864,5120) Wproj transpose.  (unchanged)
// ---------------------------------------------------------------------------
__global__ __launch_bounds__(256) void prep(const float* __restrict__ x,
                                            const float* __restrict__ Wqkv,
                                            const float* __restrict__ Wproj,
                                            __bf16* __restrict__ xb,
                                            __bf16* __restrict__ wqT,
                                            __bf16* __restrict__ wpT) {
    const int bid = blockIdx.x;
    if (bid < 4096) {  // cast
        int i = bid * 256 + threadIdx.x;
        float4 v = ((const float4*)x)[i];
        bf16x4 o = { (__bf16)v.x, (__bf16)v.y, (__bf16)v.z, (__bf16)v.w };
        ((bf16x4*)xb)[i] = o;
        return;
    }
    __shared__ float ld[64][65];
    const float* in;
    __bf16* out;
    int K, N, k0, n0;
    if (bid < 4096 + 768) {
        int j = bid - 4096;
        in = Wqkv; out = wqT; K = 1024; N = 3072;
        k0 = (j & 15) * 64; n0 = (j >> 4) * 64;
    } else {
        int j = bid - 4096 - 768;
        in = Wproj; out = wpT; K = 1024; N = 1024;
        k0 = (j & 15) * 64; n0 = (j >> 4) * 64;
    }
    #pragma unroll
    for (int i = 0; i < 16; i++) {
        int idx = i * 256 + threadIdx.x;
        int r = idx >> 6, c = idx & 63;
        ld[r][c] = in[(size_t)(k0 + r) * N + n0 + c];
    }
    __syncthreads();
    #pragma unroll
    for (int i = 0; i < 16; i++) {
        int idx = i * 256 + threadIdx.x;
        int r = idx >> 6, c = idx & 63;
        out[(size_t)(n0 + r) * K + k0 + c] = (__bf16)ld[c][r];
    }
}

// ---------------------------------------------------------------------------
// QKV GEMM: 256x256 tile, BK=64, 8 waves (2Mx4N), 512 threads, 128 KiB LDS
// double-buffer.  NEW (R2): software-pipelined fragment reads with COUNTED
// lgkmcnt so ds_read overlaps MFMA (the R1 lgkmcnt(0)-per-phase version
// serialized ~2300 cyc/tile of LDS reads against ~2480 cyc of MFMA).
//   P0: issue bfA,bfB (8 rd) ; stage Ah1(t+1) ; lgkm(4)  -> MFMA af0 x bfA
//   P1: issue af1 (8 rd)                      ; lgkm(8)  -> MFMA af0 x bfB
//   P2: stage Bh0,Bh1(t+2)                    ; lgkm(0)  -> MFMA af1 x bfA
//   P3: stage Ah0(t+2) ; vmcnt(6) ; SB ; issue af0(t+1)  -> MFMA af1 x bfB
// WAR proof: every buffer-overwriting DMA is issued after a barrier that
// each reader wave reaches only after its completion-forcing lgkm wait
// (bfA@P0-lgkm4, bfB@P1-lgkm8, af0@P0-lgkm4, af1@P2-lgkm0; B overwritten
// @P2 post-P1-SB, A-lo overwritten @P3 post-P2-SB, A-hi overwritten
// @P0(t+1) post-P3-SBs).  vmcnt(6) FIFO: issue order Ah1(t+1), Bh0(t+2),
// Bh1(t+2), Ah0(t+2) -> wait leaves exactly {Bh0,Bh1,Ah0}(t+2), completes
// all of tile t+1 before the early af0(t+1) reads.
// ---------------------------------------------------------------------------
__device__ __forceinline__ void ld8(bf16x8 (&f)[4][2], const __bf16* p0, const __bf16* p1) {
    #pragma unroll
    for (int mi = 0; mi < 4; ++mi) {
        f[mi][0] = *(const bf16x8*)(p0 + mi * 1024);
        f[mi][1] = *(const bf16x8*)(p1 + mi * 1024);
    }
}
__device__ __forceinline__ void ld4(bf16x8 (&f)[2][2], const __bf16* p0, const __bf16* p1) {
    #pragma unroll
    for (int j = 0; j < 2; ++j) {
        f[j][0] = *(const bf16x8*)(p0 + j * 1024);
        f[j][1] = *(const bf16x8*)(p1 + j * 1024);
    }
}
template <int M0, int N0>
__device__ __forceinline__ void mm8(f32x4 (&acc)[8][4], const bf16x8 (&AF)[4][2],
                                    const bf16x8 (&BF)[2][2]) {
    #pragma unroll
    for (int mi = 0; mi < 4; ++mi)
        #pragma unroll
        for (int j = 0; j < 2; ++j) {
            f32x4 c = acc[M0 + mi][N0 + j];
            c = __builtin_amdgcn_mfma_f32_16x16x32_bf16(AF[mi][0], BF[j][0], c, 0, 0, 0);
            c = __builtin_amdgcn_mfma_f32_16x16x32_bf16(AF[mi][1], BF[j][1], c, 0, 0, 0);
            acc[M0 + mi][N0 + j] = c;
        }
}

__global__ __launch_bounds__(512, 2) void gemm_qkv(const __bf16* __restrict__ A,
                                                   const __bf16* __restrict__ Bt,
                                                   const float* __restrict__ bias,
                                                   __bf16* __restrict__ Cout,
                                                   __bf16* __restrict__ vt) {
    constexpr int N = 3072;
    constexpr int NT = 16;                   // K=1024 / BK=64
    __shared__ __align__(16) __bf16 smem[65536];   // 128 KiB

    const int tid  = threadIdx.x;
    const int lane = tid & 63;
    const int wave = tid >> 6;
    const int wy = wave >> 2, wx = wave & 3;       // 2 x 4 waves
    const int l15 = lane & 15, quad = lane >> 4;
    const size_t row0 = (size_t)blockIdx.y * 256;
    const size_t col0 = (size_t)blockIdx.x * 256;

    const __bf16* const Ab  = A  + row0 * 1024;
    const __bf16* const Bb_ = Bt + col0 * 1024;

    // staging per-lane offsets (identical for every STAGE call)
    const int c0 = tid, c1 = 512 + tid;
    const int r0 = c0 >> 3, s0 = ((c0 & 7) ^ (r0 & 7));
    const int r1 = c1 >> 3, s1 = ((c1 & 7) ^ (r1 & 7));
    const int go0 = r0 * 1024 + s0 * 8, go1 = r1 * 1024 + s1 * 8;
    const int lo0 = c0 * 8, lo1 = c1 * 8;
#define STAGE(gb, lb) do { const __bf16* _g = (gb); __bf16* _l = (lb); \
        gload16(_g + go0, _l + lo0); gload16(_g + go1, _l + lo1); } while (0)

    // fragment per-lane offsets (elements)
    const int x7 = l15 & 7;
    const int ch0 = (quad ^ x7) * 8, ch1 = ((4 + quad) ^ x7) * 8;
    const int aoff0 = (wy * 128 + l15) * 64 + ch0;
    const int aoff1 = (wy * 128 + l15) * 64 + ch1;
    const int boff0 = (wx * 64 + l15) * 64 + ch0;
    const int boff1 = (wx * 64 + l15) * 64 + ch1;

    f32x4 acc[8][4] = {};
    bf16x8 af0[4][2], af1[4][2], bfA[2][2], bfB[2][2];

    // ---- prologue: tile0 (4 halves) + Bh0(1),Bh1(1),Ah0(1) = 14 loads ----
    STAGE(Ab,                          smem);                    // Ah0(0)
    STAGE(Ab  + (size_t)128 * 1024,    smem + 8192);             // Ah1(0)
    STAGE(Bb_,                         smem + 32768);            // Bh0(0)
    STAGE(Bb_ + (size_t)128 * 1024,    smem + 32768 + 8192);     // Bh1(0)
    STAGE(Bb_ + 64,                    smem + 32768 + 16384);          // Bh0(1)
    STAGE(Bb_ + (size_t)128 * 1024 + 64, smem + 32768 + 16384 + 8192); // Bh1(1)
    STAGE(Ab  + 64,                    smem + 16384);            // Ah0(1)
    VMC6(); SB(); SCB();
    ld8(af0, smem + aoff0, smem + aoff1);                        // af0(0)
    SCB();

    for (int t = 0; t < NT; ++t) {
        const int cur = t & 1;
        __bf16* const AsC = smem + cur * 16384;
        __bf16* const BsC = smem + 32768 + cur * 16384;
        __bf16* const AsN = smem + (cur ^ 1) * 16384;

        // ---------------- P0 ----------------
        ld4(bfA, BsC + boff0, BsC + boff1);
        SCB();                                       // pin FIFO: bfA before bfB
        ld4(bfB, BsC + 2048 + boff0, BsC + 2048 + boff1);
        if (t + 1 < NT) STAGE(Ab + (size_t)128 * 1024 + (t + 1) * 64, AsN + 8192);
        LGKM4(); SCB();                              // af0 + bfA ready, bfB flying
        __builtin_amdgcn_s_setprio(1);
        mm8<0, 0>(acc, af0, bfA);
        __builtin_amdgcn_s_setprio(0);
        SB(); SCB();

        // ---------------- P1 ----------------
        ld8(af1, AsC + 4096 + aoff0, AsC + 4096 + aoff1);
        LGKM8(); SCB();                              // bfB ready, af1 flying
        __builtin_amdgcn_s_setprio(1);
        mm8<0, 2>(acc, af0, bfB);
        __builtin_amdgcn_s_setprio(0);
        SB(); SCB();

        // ---------------- P2 ----------------
        if (t + 2 < NT) {
            STAGE(Bb_ + (t + 2) * 64, BsC);
            STAGE(Bb_ + (size_t)128 * 1024 + (t + 2) * 64, BsC + 8192);
        }
        LGKM0(); SCB();                              // af1 ready
        __builtin_amdgcn_s_setprio(1);
        mm8<4, 0>(acc, af1, bfA);
        __builtin_amdgcn_s_setprio(0);
        SB(); SCB();

        // ---------------- P3 ----------------
        if (t + 2 < NT) {
            STAGE(Ab + (t + 2) * 64, AsC);
            VMC6();                                  // all of tile t+1 landed
        } else if (t + 1 < NT) {
            VMC0();                                  // tail: no t+2 prefetch
        }
        SB(); SCB();
        if (t + 1 < NT) ld8(af0, AsN + aoff0, AsN + aoff1);   // early af0(t+1)
        SCB();
        __builtin_amdgcn_s_setprio(1);
        mm8<4, 2>(acc, af1, bfB);
        __builtin_amdgcn_s_setprio(0);
        SB(); SCB();
    }
#undef STAGE

    // ---- epilogue: two 128-row slices through LDS (stride 264) ----
    const float scale = (col0 < 1024) ? 0.125f : 1.0f;
    const int isV = (col0 >= 2048);
    for (int sl = 0; sl < 2; ++sl) {
        if (wy == sl) {
            #pragma unroll
            for (int nj = 0; nj < 4; ++nj) {
                const int cl = wx * 64 + nj * 16 + l15;
                const float bj = bias[col0 + cl];
                #pragma unroll
                for (int mi = 0; mi < 8; ++mi) {
                    #pragma unroll
                    for (int r = 0; r < 4; ++r)
                        smem[(mi * 16 + quad * 4 + r) * 264 + cl] =
                            (__bf16)((acc[mi][nj][r] + bj) * scale);
                }
            }
        }
        __syncthreads();
        #pragma unroll
        for (int p = 0; p < 8; ++p) {
            const int idx = p * 512 + tid;       // 0..4095
            const int row = idx >> 5, ch = idx & 31;
            bf16x8 v = *(const bf16x8*)&smem[row * 264 + ch * 8];
            *(bf16x8*)&Cout[(row0 + sl * 128 + row) * N + col0 + ch * 8] = v;
        }
        if (isV) {  // V block: also write vt[b][h][d][t]
            const int bidx = (int)(row0 >> 10);
            const int t0g  = (int)(row0 & 1023) + sl * 128;
            const int cl   = tid & 255;          // tile column 0..255
            const int th   = tid >> 8;           // 0..1
            const int hd   = (int)(col0 - 2048) + cl;
            const size_t vrow = ((size_t)((bidx * Hh + (hd >> 6)) * 64 + (hd & 63))) * Tt + t0g;
            #pragma unroll
            for (int p = 0; p < 8; ++p) {
                const int tch = th * 8 + p;      // 0..15 (x8 rows)
                bf16x8 v;
                #pragma unroll
                for (int u = 0; u < 8; ++u) v[u] = smem[(tch * 8 + u) * 264 + cl];
                *(bf16x8*)&vt[vrow + tch * 8] = v;
            }
        }
        __syncthreads();
    }
}

// ---------------------------------------------------------------------------
// 128x64-tile GEMM (proj), BK=64, single-buffered.  (unchanged)
// ---------------------------------------------------------------------------
__global__ __launch_bounds__(256) void gemm_bf16_n64(const __bf16* __restrict__ A,
                                                     const __bf16* __restrict__ Bt,
                                                     const float* __restrict__ bias,
                                                     float* __restrict__ Cout,
                                                     int M, int N, int K) {
    __shared__ __align__(16) __bf16 As[128 * 64];
    __shared__ __align__(16) __bf16 Bs[64 * 64];
    const int tid  = threadIdx.x;
    const int lane = tid & 63;
    const int wave = tid >> 6;
    const int wy = wave >> 1, wx = wave & 1;
    const int l15 = lane & 15, quad = lane >> 4;
    const size_t row0 = (size_t)blockIdx.y * 128;
    const size_t col0 = (size_t)blockIdx.x * 64;

    f32x4 acc[4][2] = {};

    for (int k0 = 0; k0 < K; k0 += 64) {
        #pragma unroll
        for (int i = 0; i < 4; i++) {
            int c = i * 256 + tid;
            int r = c >> 3, seg = (c & 7) ^ (r & 7);
            gload16(&A[(row0 + r) * K + k0 + seg * 8], &As[c * 8]);
        }
        #pragma unroll
        for (int i = 0; i < 2; i++) {
            int c = i * 256 + tid;
            int r = c >> 3, seg = (c & 7) ^ (r & 7);
            gload16(&Bt[(col0 + r) * K + k0 + seg * 8], &Bs[c * 8]);
        }
        __syncthreads();
        #pragma unroll
        for (int kc = 0; kc < 2; kc++) {
            bf16x8 af[4], bfr[2];
            #pragma unroll
            for (int i = 0; i < 4; i++)
                af[i] = *(const bf16x8*)&As[(wy * 64 + i * 16 + l15) * 64 +
                                            (((kc * 4 + quad) ^ (l15 & 7)) * 8)];
            #pragma unroll
            for (int j = 0; j < 2; j++)
                bfr[j] = *(const bf16x8*)&Bs[(wx * 32 + j * 16 + l15) * 64 +
                                             (((kc * 4 + quad) ^ (l15 & 7)) * 8)];
            #pragma unroll
            for (int i = 0; i < 4; i++)
                #pragma unroll
                for (int j = 0; j < 2; j++)
                    acc[i][j] = __builtin_amdgcn_mfma_f32_16x16x32_bf16(af[i], bfr[j], acc[i][j], 0, 0, 0);
        }
        __syncthreads();
    }

    #pragma unroll
    for (int j = 0; j < 2; j++) {
        const size_t col = col0 + wx * 32 + j * 16 + l15;
        const float bj = bias[col];
        #pragma unroll
        for (int i = 0; i < 4; i++) {
            const size_t row = row0 + wy * 64 + i * 16 + quad * 4;
            #pragma unroll
            for (int r = 0; r < 4; r++)
                Cout[(row + r) * N + col] = acc[i][j][r] + bj;
        }
    }
}

// ---------------------------------------------------------------------------
// Flash attention (S^T = K @ Q^T).  (unchanged)
// ---------------------------------------------------------------------------
__global__ __launch_bounds__(256, 4) void attn_mfma(const __bf16* __restrict__ qkv,
                                                    const __bf16* __restrict__ vt,
                                                    const int* __restrict__ mask,
                                                    __bf16* __restrict__ att) {
    __shared__ __align__(16) __bf16 Ks[2][4096];
    __shared__ __align__(16) __bf16 Vs[2][4096];
    __shared__ __align__(16) __bf16 Ps[4][1024];

    const int h  = blockIdx.x & 15;
    const int b  = blockIdx.x >> 4;
    const int qt = 15 - blockIdx.y;  // LPT: longest blocks dispatch first
    const int tid = threadIdx.x, lane = tid & 63, wave = tid >> 6;
    const int l15 = lane & 15, quad = lane >> 4;

    // stage Q (swizzled) through Ks[0]
    #pragma unroll
    for (int i = 0; i < 2; i++) {
        int c = i * 256 + tid;
        int rr = c >> 3, ch = c & 7;
        gload16(&qkv[((size_t)(b * Tt + qt * 64 + rr)) * 3072 + h * 64 + ((ch ^ (rr & 7)) * 8)],
                &Ks[0][c * 8]);
    }

    // mask ballot pass: tile p's 64 bits end up in lane-group (lane&15)==p
    uint32_t mlo = 0, mhi = 0;
    for (int p = 0; p < 16; p++) {
        unsigned long long bal = __ballot(mask[b * Tt + p * 64 + lane] != 0);
        if ((lane & 15) == p) { mlo = (uint32_t)bal; mhi = (uint32_t)(bal >> 32); }
    }

    __syncthreads();
    bf16x8 qf0 = *(const bf16x8*)&Ks[0][(wave * 16 + l15) * 64 + ((quad ^ (l15 & 7)) * 8)];
    bf16x8 qf1 = *(const bf16x8*)&Ks[0][(wave * 16 + l15) * 64 + (((4 + quad) ^ (l15 & 7)) * 8)];
    __syncthreads();  // Q frag reads done -> Ks[0] reusable

    #pragma unroll
    for (int i = 0; i < 2; i++) {
        int c = i * 256 + tid;
        int rr = c >> 3, ch = c & 7, sw = ((ch ^ (rr & 7)) * 8);
        gload16(&qkv[((size_t)(b * Tt + rr)) * 3072 + 1024 + h * 64 + sw], &Ks[0][c * 8]);
        gload16(&vt[((size_t)((b * Hh + h) * 64 + rr)) * Tt + sw], &Vs[0][c * 8]);
    }

    f32x4 Oacc[4] = {};
    float lsum = 0.0f;

    for (int kt = 0; kt <= qt; kt++) {
        __syncthreads();  // DMA(kt) complete (issued a full compute phase ago)
        const int cur = kt & 1;
        if (kt < qt) {
            #pragma unroll
            for (int i = 0; i < 2; i++) {
                int c = i * 256 + tid;
                int rr = c >> 3, ch = c & 7, sw = ((ch ^ (rr & 7)) * 8);
                gload16(&qkv[((size_t)(b * Tt + (kt + 1) * 64 + rr)) * 3072 + 1024 + h * 64 + sw],
                        &Ks[cur ^ 1][c * 8]);
                gload16(&vt[((size_t)((b * Hh + h) * 64 + rr)) * Tt + (kt + 1) * 64 + sw],
                        &Vs[cur ^ 1][c * 8]);
            }
        }

        // mask bits for this tile (uniform readlane, no memory access)
        const uint32_t lo = (uint32_t)__builtin_amdgcn_readlane((int)mlo, kt);
        const uint32_t hi = (uint32_t)__builtin_amdgcn_readlane((int)mhi, kt);

        bf16x8 ak[4][2];
        #pragma unroll
        for (int j = 0; j < 4; j++)
            #pragma unroll
            for (int kc = 0; kc < 2; kc++)
                ak[j][kc] = *(const bf16x8*)&Ks[cur][(j * 16 + l15) * 64 +
                                                     (((kc * 4 + quad) ^ (l15 & 7)) * 8)];
        #pragma unroll
        for (int j = 0; j < 4; j++) {
            f32x4 st = {};
            st = __builtin_amdgcn_mfma_f32_16x16x32_bf16(ak[j][0], qf0, st, 0, 0, 0);
            st = __builtin_amdgcn_mfma_f32_16x16x32_bf16(ak[j][1], qf1, st, 0, 0, 0);
            const uint32_t fld = (j < 2) ? (lo >> (j * 16)) : (hi >> ((j - 2) * 16));
            bf16x4 pv;
            #pragma unroll
            for (int r = 0; r < 4; r++) {
                const int tloc = j * 16 + quad * 4 + r;
                bool keep = (fld >> (quad * 4 + r)) & 1;
                if (kt == qt) keep = keep && (tloc <= wave * 16 + l15);
                const float pe = keep ? __expf(st[r]) : 0.0f;
                lsum += pe;
                pv[r] = (__bf16)pe;
            }
            *(bf16x4*)&Ps[wave][l15 * 64 + (((j * 4 + quad) ^ ((l15 & 7) << 1)) * 4)] = pv;
        }

        bf16x8 av[4][2];
        #pragma unroll
        for (int n = 0; n < 4; n++)
            #pragma unroll
            for (int kc = 0; kc < 2; kc++)
                av[n][kc] = *(const bf16x8*)&Vs[cur][(n * 16 + l15) * 64 +
                                                     (((kc * 4 + quad) ^ (l15 & 7)) * 8)];
        bf16x8 p0 = *(const bf16x8*)&Ps[wave][l15 * 64 + (((2 * quad) ^ ((l15 & 7) << 1)) * 4)];
        bf16x8 p1 = *(const bf16x8*)&Ps[wave][l15 * 64 + (((2 * (4 + quad)) ^ ((l15 & 7) << 1)) * 4)];
        #pragma unroll
        for (int n = 0; n < 4; n++) {
            Oacc[n] = __builtin_amdgcn_mfma_f32_16x16x32_bf16(av[n][0], p0, Oacc[n], 0, 0, 0);
            Oacc[n] = __builtin_amdgcn_mfma_f32_16x16x32_bf16(av[n][1], p1, Oacc[n], 0, 0, 0);
        }
    }

    float lt = lsum;
    lt += __shfl_xor(lt, 16);
    lt += __shfl_xor(lt, 32);
    const float inv = 1.0f / lt;
    const int q = qt * 64 + wave * 16 + l15;
    #pragma unroll
    for (int n = 0; n < 4; n++) {
        bf16x4 o;
        #pragma unroll
        for (int r = 0; r < 4; r++) o[r] = (__bf16)(Oacc[n][r] * inv);
        *(bf16x4*)&att[((size_t)(b * Tt + q)) * Dd + h * 64 + n * 16 + quad * 4] = o;
    }
}

// ---------------------------------------------------------------------------
extern "C" void kernel_launch(void* const* d_in, const int* in_sizes, int n_in,
                              void* d_out, int out_size, void* d_ws, size_t ws_size,
                              hipStream_t stream) {
    const float* x     = (const float*)d_in[0];
    const float* Wqkv  = (const float*)d_in[1];
    const float* bqkv  = (const float*)d_in[2];
    const float* Wproj = (const float*)d_in[3];
    const float* bproj = (const float*)d_in[4];
    const int*   mask  = (const int*)d_in[5];
    float* out = (float*)d_out;

    __bf16* xb  = (__bf16*)d_ws;                         // 4096*1024
    __bf16* wqT = xb  + (size_t)4096 * 1024;             // 3072*1024
    __bf16* wpT = wqT + (size_t)3072 * 1024;             // 1024*1024
    __bf16* qkv = wpT + (size_t)1024 * 1024;             // 4096*3072
    __bf16* vt  = qkv + (size_t)4096 * 3072;             // 4*16*64*1024
    __bf16* att = vt  + (size_t)4 * 16 * 64 * 1024;      // 4096*1024

    prep<<<4096 + 768 + 256, 256, 0, stream>>>(x, Wqkv, Wproj, xb, wqT, wpT);

    gemm_qkv<<<dim3(12, 16), 512, 0, stream>>>(xb, wqT, bqkv, qkv, vt);

    attn_mfma<<<dim3(64, 16), 256, 0, stream>>>(qkv, vt, mask, att);

    gemm_bf16_n64<<<dim3(16, 32), 256, 0, stream>>>(att, wpT, bproj, out, 4096, 1024, 1024);
}

// Round 3
// 163.358 us; speedup vs baseline: 1.0209x; 1.0118x over previous
//
#include <hip/hip_runtime.h>
#include <hip/hip_bf16.h>
#include <cstddef>
#include <cstdint>

#define Bb 4
#define Tt 1024
#define Dd 1024
#define Hh 16

typedef __bf16 bf16x8 __attribute__((ext_vector_type(8)));
typedef __bf16 bf16x4 __attribute__((ext_vector_type(4)));
typedef float  f32x4  __attribute__((ext_vector_type(4)));

__device__ __forceinline__ void gload16(const void* g, void* l) {
    __builtin_amdgcn_global_load_lds(
        (const __attribute__((address_space(1))) void*)g,
        (__attribute__((address_space(3))) void*)l, 16, 0, 0);
}

// ---------------------------------------------------------------------------
// Fused prep: [0,4096) cast x -> bf16; [4096,4864) Wqkv transpose;
// [4864,5120) Wproj transpose.  NEW (R3): transpose stores vectorized to
// bf16x4 (scalar 2B stores were the write bottleneck on 18 MB of W data).
// ---------------------------------------------------------------------------
__global__ __launch_bounds__(256) void prep(const float* __restrict__ x,
                                            const float* __restrict__ Wqkv,
                                            const float* __restrict__ Wproj,
                                            __bf16* __restrict__ xb,
                                            __bf16* __restrict__ wqT,
                                            __bf16* __restrict__ wpT) {
    const int bid = blockIdx.x;
    if (bid < 4096) {  // cast
        int i = bid * 256 + threadIdx.x;
        float4 v = ((const float4*)x)[i];
        bf16x4 o = { (__bf16)v.x, (__bf16)v.y, (__bf16)v.z, (__bf16)v.w };
        ((bf16x4*)xb)[i] = o;
        return;
    }
    __shared__ float ld[64][65];
    const float* in;
    __bf16* out;
    int K, N, k0, n0;
    if (bid < 4096 + 768) {
        int j = bid - 4096;
        in = Wqkv; out = wqT; K = 1024; N = 3072;
        k0 = (j & 15) * 64; n0 = (j >> 4) * 64;
    } else {
        int j = bid - 4096 - 768;
        in = Wproj; out = wpT; K = 1024; N = 1024;
        k0 = (j & 15) * 64; n0 = (j >> 4) * 64;
    }
    #pragma unroll
    for (int i = 0; i < 16; i++) {
        int idx = i * 256 + threadIdx.x;
        int r = idx >> 6, c = idx & 63;
        ld[r][c] = in[(size_t)(k0 + r) * N + n0 + c];
    }
    __syncthreads();
    #pragma unroll
    for (int i = 0; i < 4; i++) {
        int idx = i * 256 + threadIdx.x;      // 0..1023: r = out-row, c4 = col quad
        int r = idx >> 4, c4 = (idx & 15) * 4;
        bf16x4 o = { (__bf16)ld[c4][r], (__bf16)ld[c4 + 1][r],
                     (__bf16)ld[c4 + 2][r], (__bf16)ld[c4 + 3][r] };
        *(bf16x4*)&out[(size_t)(n0 + r) * K + k0 + c4] = o;
    }
}

// ---------------------------------------------------------------------------
// 128x128 MFMA GEMM (QKV), BK=32, double-buffered, one barrier/iter.
// (R3: exact revert to the 42.9 µs R0 version — both 256²/8-phase ports
// regressed: 192-block grid leaves 64 CUs idle and 1 block/CU kills the
// cross-block overlap that this 3-block/CU structure gets for free.)
// Epilogue: acc -> padded LDS tile -> coalesced bf16x8 stores; for V columns
// (col0 >= 2048) ALSO emits the transposed vt[b][h][d][t] copy from the same
// LDS tile.  Q columns (<1024) pre-scaled by 0.125.
// ---------------------------------------------------------------------------
__global__ __launch_bounds__(256) void gemm_qkv(const __bf16* __restrict__ A,
                                                const __bf16* __restrict__ Bt,
                                                const float* __restrict__ bias,
                                                __bf16* __restrict__ Cout,
                                                __bf16* __restrict__ vt,
                                                int M, int N, int K) {
    __shared__ __align__(16) __bf16 smem[17408];  // 34816 B
    __bf16* const As = smem;          // [2][4096]
    __bf16* const Bs = smem + 8192;   // [2][4096]

    const int tid  = threadIdx.x;
    const int lane = tid & 63;
    const int wave = tid >> 6;
    const int wy = wave >> 1, wx = wave & 1;
    const int l15 = lane & 15, quad = lane >> 4;
    const size_t row0 = (size_t)blockIdx.y * 128;
    const size_t col0 = (size_t)blockIdx.x * 128;

    f32x4 acc[4][4] = {};

    #pragma unroll
    for (int i = 0; i < 2; i++) {
        int c = i * 256 + tid;
        int r = c >> 2, seg = (c & 3) ^ ((r >> 1) & 3);
        gload16(&A[(row0 + r) * K + seg * 8], &As[c * 8]);
        gload16(&Bt[(col0 + r) * K + seg * 8], &Bs[c * 8]);
    }

    const int niter = K >> 5;  // 32
    for (int it = 0; it < niter; it++) {
        __syncthreads();
        const int cur = it & 1;
        if (it + 1 < niter) {
            const int k0 = (it + 1) << 5;
            #pragma unroll
            for (int i = 0; i < 2; i++) {
                int c = i * 256 + tid;
                int r = c >> 2, seg = (c & 3) ^ ((r >> 1) & 3);
                gload16(&A[(row0 + r) * K + k0 + seg * 8], &As[(cur ^ 1) * 4096 + c * 8]);
                gload16(&Bt[(col0 + r) * K + k0 + seg * 8], &Bs[(cur ^ 1) * 4096 + c * 8]);
            }
        }
        bf16x8 af[4], bfr[4];
        #pragma unroll
        for (int i = 0; i < 4; i++) {
            const int r = wy * 64 + i * 16 + l15;
            af[i] = *(const bf16x8*)&As[cur * 4096 + r * 32 + ((quad ^ ((r >> 1) & 3)) * 8)];
        }
        #pragma unroll
        for (int j = 0; j < 4; j++) {
            const int r = wx * 64 + j * 16 + l15;
            bfr[j] = *(const bf16x8*)&Bs[cur * 4096 + r * 32 + ((quad ^ ((r >> 1) & 3)) * 8)];
        }
        #pragma unroll
        for (int i = 0; i < 4; i++)
            #pragma unroll
            for (int j = 0; j < 4; j++)
                acc[i][j] = __builtin_amdgcn_mfma_f32_16x16x32_bf16(af[i], bfr[j], acc[i][j], 0, 0, 0);
    }

    // ---- epilogue: bias+scale -> LDS tile (stride 132) -> coalesced stores ----
    __syncthreads();
    #pragma unroll
    for (int j = 0; j < 4; j++) {
        const int cl = wx * 64 + j * 16 + l15;
        const size_t col = col0 + cl;
        const float bj = bias[col];
        const float scale = (col < 1024) ? 0.125f : 1.0f;
        #pragma unroll
        for (int i = 0; i < 4; i++) {
            const int rl = wy * 64 + i * 16 + quad * 4;
            #pragma unroll
            for (int r = 0; r < 4; r++)
                smem[(rl + r) * 132 + cl] = (__bf16)((acc[i][j][r] + bj) * scale);
        }
    }
    __syncthreads();
    #pragma unroll
    for (int p = 0; p < 8; p++) {
        const int row = p * 16 + (tid >> 4);
        const int ch  = tid & 15;
        bf16x8 v = *(const bf16x8*)&smem[row * 132 + ch * 8];
        *(bf16x8*)&Cout[(row0 + row) * N + col0 + ch * 8] = v;
    }
    if (col0 >= 2048) {  // V block: also write vt[b][h][d][t] (t = M rows)
        const int bidx = (int)(row0 >> 10);
        const int t0g  = (int)(row0 & 1023);
        const int cl   = tid >> 1;          // tile column 0..127
        const int half = tid & 1;           // t-half 0..1
        const int hd   = (int)(col0 - 2048) + cl;
        const size_t vrow = ((size_t)((bidx * Hh + (hd >> 6)) * 64 + (hd & 63))) * Tt + t0g;
        #pragma unroll
        for (int s = 0; s < 8; s++) {
            const int t = half * 64 + s * 8;
            bf16x8 v;
            #pragma unroll
            for (int u = 0; u < 8; u++) v[u] = smem[(t + u) * 132 + cl];
            *(bf16x8*)&vt[vrow + t] = v;
        }
    }
}

// ---------------------------------------------------------------------------
// 128x64-tile GEMM (proj), BK=64.  NEW (R3): double-buffered with the DMA
// for tile t+1 issued right after the single per-iter barrier (R0-qkv
// pattern).  The old form did {stage; barrier; compute; barrier} — the
// barrier immediately drained the just-issued DMA with nothing overlapping,
// i.e. serial HBM/L2 latency every iteration.  Now DMA(t+1) has the whole
// 16-MFMA compute phase of tile t to land.  WAR identical to gemm_qkv:
// DMA(t+1) targets buf^1, whose ds_reads completed before this barrier.
// ---------------------------------------------------------------------------
__global__ __launch_bounds__(256) void gemm_bf16_n64(const __bf16* __restrict__ A,
                                                     const __bf16* __restrict__ Bt,
                                                     const float* __restrict__ bias,
                                                     float* __restrict__ Cout,
                                                     int M, int N, int K) {
    __shared__ __align__(16) __bf16 As[2][128 * 64];
    __shared__ __align__(16) __bf16 Bs[2][64 * 64];
    const int tid  = threadIdx.x;
    const int lane = tid & 63;
    const int wave = tid >> 6;
    const int wy = wave >> 1, wx = wave & 1;
    const int l15 = lane & 15, quad = lane >> 4;
    const size_t row0 = (size_t)blockIdx.y * 128;
    const size_t col0 = (size_t)blockIdx.x * 64;

    f32x4 acc[4][2] = {};

    // prologue: stage tile 0
    #pragma unroll
    for (int i = 0; i < 4; i++) {
        int c = i * 256 + tid;
        int r = c >> 3, seg = (c & 7) ^ (r & 7);
        gload16(&A[(row0 + r) * K + seg * 8], &As[0][c * 8]);
    }
    #pragma unroll
    for (int i = 0; i < 2; i++) {
        int c = i * 256 + tid;
        int r = c >> 3, seg = (c & 7) ^ (r & 7);
        gload16(&Bt[(col0 + r) * K + seg * 8], &Bs[0][c * 8]);
    }

    const int niter = K >> 6;  // 16
    for (int it = 0; it < niter; ++it) {
        __syncthreads();                       // DMA(it) complete + WAR
        const int cur = it & 1;
        if (it + 1 < niter) {
            const int k0 = (it + 1) << 6;
            #pragma unroll
            for (int i = 0; i < 4; i++) {
                int c = i * 256 + tid;
                int r = c >> 3, seg = (c & 7) ^ (r & 7);
                gload16(&A[(row0 + r) * K + k0 + seg * 8], &As[cur ^ 1][c * 8]);
            }
            #pragma unroll
            for (int i = 0; i < 2; i++) {
                int c = i * 256 + tid;
                int r = c >> 3, seg = (c & 7) ^ (r & 7);
                gload16(&Bt[(col0 + r) * K + k0 + seg * 8], &Bs[cur ^ 1][c * 8]);
            }
        }
        #pragma unroll
        for (int kc = 0; kc < 2; kc++) {
            bf16x8 af[4], bfr[2];
            #pragma unroll
            for (int i = 0; i < 4; i++)
                af[i] = *(const bf16x8*)&As[cur][(wy * 64 + i * 16 + l15) * 64 +
                                                 (((kc * 4 + quad) ^ (l15 & 7)) * 8)];
            #pragma unroll
            for (int j = 0; j < 2; j++)
                bfr[j] = *(const bf16x8*)&Bs[cur][(wx * 32 + j * 16 + l15) * 64 +
                                                  (((kc * 4 + quad) ^ (l15 & 7)) * 8)];
            #pragma unroll
            for (int i = 0; i < 4; i++)
                #pragma unroll
                for (int j = 0; j < 2; j++)
                    acc[i][j] = __builtin_amdgcn_mfma_f32_16x16x32_bf16(af[i], bfr[j], acc[i][j], 0, 0, 0);
        }
    }

    #pragma unroll
    for (int j = 0; j < 2; j++) {
        const size_t col = col0 + wx * 32 + j * 16 + l15;
        const float bj = bias[col];
        #pragma unroll
        for (int i = 0; i < 4; i++) {
            const size_t row = row0 + wy * 64 + i * 16 + quad * 4;
            #pragma unroll
            for (int r = 0; r < 4; r++)
                Cout[(row + r) * N + col] = acc[i][j][r] + bj;
        }
    }
}

// ---------------------------------------------------------------------------
// Flash attention (S^T = K @ Q^T).  (unchanged)
// ---------------------------------------------------------------------------
__global__ __launch_bounds__(256, 4) void attn_mfma(const __bf16* __restrict__ qkv,
                                                    const __bf16* __restrict__ vt,
                                                    const int* __restrict__ mask,
                                                    __bf16* __restrict__ att) {
    __shared__ __align__(16) __bf16 Ks[2][4096];
    __shared__ __align__(16) __bf16 Vs[2][4096];
    __shared__ __align__(16) __bf16 Ps[4][1024];

    const int h  = blockIdx.x & 15;
    const int b  = blockIdx.x >> 4;
    const int qt = 15 - blockIdx.y;  // LPT: longest blocks dispatch first
    const int tid = threadIdx.x, lane = tid & 63, wave = tid >> 6;
    const int l15 = lane & 15, quad = lane >> 4;

    // stage Q (swizzled) through Ks[0]
    #pragma unroll
    for (int i = 0; i < 2; i++) {
        int c = i * 256 + tid;
        int rr = c >> 3, ch = c & 7;
        gload16(&qkv[((size_t)(b * Tt + qt * 64 + rr)) * 3072 + h * 64 + ((ch ^ (rr & 7)) * 8)],
                &Ks[0][c * 8]);
    }

    // mask ballot pass: tile p's 64 bits end up in lane-group (lane&15)==p
    uint32_t mlo = 0, mhi = 0;
    for (int p = 0; p < 16; p++) {
        unsigned long long bal = __ballot(mask[b * Tt + p * 64 + lane] != 0);
        if ((lane & 15) == p) { mlo = (uint32_t)bal; mhi = (uint32_t)(bal >> 32); }
    }

    __syncthreads();
    bf16x8 qf0 = *(const bf16x8*)&Ks[0][(wave * 16 + l15) * 64 + ((quad ^ (l15 & 7)) * 8)];
    bf16x8 qf1 = *(const bf16x8*)&Ks[0][(wave * 16 + l15) * 64 + (((4 + quad) ^ (l15 & 7)) * 8)];
    __syncthreads();  // Q frag reads done -> Ks[0] reusable

    #pragma unroll
    for (int i = 0; i < 2; i++) {
        int c = i * 256 + tid;
        int rr = c >> 3, ch = c & 7, sw = ((ch ^ (rr & 7)) * 8);
        gload16(&qkv[((size_t)(b * Tt + rr)) * 3072 + 1024 + h * 64 + sw], &Ks[0][c * 8]);
        gload16(&vt[((size_t)((b * Hh + h) * 64 + rr)) * Tt + sw], &Vs[0][c * 8]);
    }

    f32x4 Oacc[4] = {};
    float lsum = 0.0f;

    for (int kt = 0; kt <= qt; kt++) {
        __syncthreads();  // DMA(kt) complete (issued a full compute phase ago)
        const int cur = kt & 1;
        if (kt < qt) {
            #pragma unroll
            for (int i = 0; i < 2; i++) {
                int c = i * 256 + tid;
                int rr = c >> 3, ch = c & 7, sw = ((ch ^ (rr & 7)) * 8);
                gload16(&qkv[((size_t)(b * Tt + (kt + 1) * 64 + rr)) * 3072 + 1024 + h * 64 + sw],
                        &Ks[cur ^ 1][c * 8]);
                gload16(&vt[((size_t)((b * Hh + h) * 64 + rr)) * Tt + (kt + 1) * 64 + sw],
                        &Vs[cur ^ 1][c * 8]);
            }
        }

        // mask bits for this tile (uniform readlane, no memory access)
        const uint32_t lo = (uint32_t)__builtin_amdgcn_readlane((int)mlo, kt);
        const uint32_t hi = (uint32_t)__builtin_amdgcn_readlane((int)mhi, kt);

        bf16x8 ak[4][2];
        #pragma unroll
        for (int j = 0; j < 4; j++)
            #pragma unroll
            for (int kc = 0; kc < 2; kc++)
                ak[j][kc] = *(const bf16x8*)&Ks[cur][(j * 16 + l15) * 64 +
                                                     (((kc * 4 + quad) ^ (l15 & 7)) * 8)];
        #pragma unroll
        for (int j = 0; j < 4; j++) {
            f32x4 st = {};
            st = __builtin_amdgcn_mfma_f32_16x16x32_bf16(ak[j][0], qf0, st, 0, 0, 0);
            st = __builtin_amdgcn_mfma_f32_16x16x32_bf16(ak[j][1], qf1, st, 0, 0, 0);
            const uint32_t fld = (j < 2) ? (lo >> (j * 16)) : (hi >> ((j - 2) * 16));
            bf16x4 pv;
            #pragma unroll
            for (int r = 0; r < 4; r++) {
                const int tloc = j * 16 + quad * 4 + r;
                bool keep = (fld >> (quad * 4 + r)) & 1;
                if (kt == qt) keep = keep && (tloc <= wave * 16 + l15);
                const float pe = keep ? __expf(st[r]) : 0.0f;
                lsum += pe;
                pv[r] = (__bf16)pe;
            }
            *(bf16x4*)&Ps[wave][l15 * 64 + (((j * 4 + quad) ^ ((l15 & 7) << 1)) * 4)] = pv;
        }

        bf16x8 av[4][2];
        #pragma unroll
        for (int n = 0; n < 4; n++)
            #pragma unroll
            for (int kc = 0; kc < 2; kc++)
                av[n][kc] = *(const bf16x8*)&Vs[cur][(n * 16 + l15) * 64 +
                                                     (((kc * 4 + quad) ^ (l15 & 7)) * 8)];
        bf16x8 p0 = *(const bf16x8*)&Ps[wave][l15 * 64 + (((2 * quad) ^ ((l15 & 7) << 1)) * 4)];
        bf16x8 p1 = *(const bf16x8*)&Ps[wave][l15 * 64 + (((2 * (4 + quad)) ^ ((l15 & 7) << 1)) * 4)];
        #pragma unroll
        for (int n = 0; n < 4; n++) {
            Oacc[n] = __builtin_amdgcn_mfma_f32_16x16x32_bf16(av[n][0], p0, Oacc[n], 0, 0, 0);
            Oacc[n] = __builtin_amdgcn_mfma_f32_16x16x32_bf16(av[n][1], p1, Oacc[n], 0, 0, 0);
        }
    }

    float lt = lsum;
    lt += __shfl_xor(lt, 16);
    lt += __shfl_xor(lt, 32);
    const float inv = 1.0f / lt;
    const int q = qt * 64 + wave * 16 + l15;
    #pragma unroll
    for (int n = 0; n < 4; n++) {
        bf16x4 o;
        #pragma unroll
        for (int r = 0; r < 4; r++) o[r] = (__bf16)(Oacc[n][r] * inv);
        *(bf16x4*)&att[((size_t)(b * Tt + q)) * Dd + h * 64 + n * 16 + quad * 4] = o;
    }
}

// ---------------------------------------------------------------------------
extern "C" void kernel_launch(void* const* d_in, const int* in_sizes, int n_in,
                              void* d_out, int out_size, void* d_ws, size_t ws_size,
                              hipStream_t stream) {
    const float* x     = (const float*)d_in[0];
    const float* Wqkv  = (const float*)d_in[1];
    const float* bqkv  = (const float*)d_in[2];
    const float* Wproj = (const float*)d_in[3];
    const float* bproj = (const float*)d_in[4];
    const int*   mask  = (const int*)d_in[5];
    float* out = (float*)d_out;

    __bf16* xb  = (__bf16*)d_ws;                         // 4096*1024
    __bf16* wqT = xb  + (size_t)4096 * 1024;             // 3072*1024
    __bf16* wpT = wqT + (size_t)3072 * 1024;             // 1024*1024
    __bf16* qkv = wpT + (size_t)1024 * 1024;             // 4096*3072
    __bf16* vt  = qkv + (size_t)4096 * 3072;             // 4*16*64*1024
    __bf16* att = vt  + (size_t)4 * 16 * 64 * 1024;      // 4096*1024

    prep<<<4096 + 768 + 256, 256, 0, stream>>>(x, Wqkv, Wproj, xb, wqT, wpT);

    gemm_qkv<<<dim3(24, 32), 256, 0, stream>>>(xb, wqT, bqkv, qkv, vt, 4096, 3072, 1024);

    attn_mfma<<<dim3(64, 16), 256, 0, stream>>>(qkv, vt, mask, att);

    gemm_bf16_n64<<<dim3(16, 32), 256, 0, stream>>>(att, wpT, bproj, out, 4096, 1024, 1024);
}

// Round 4
// 161.100 us; speedup vs baseline: 1.0352x; 1.0140x over previous
//
#include <hip/hip_runtime.h>
#include <hip/hip_bf16.h>
#include <cstddef>
#include <cstdint>

#define Bb 4
#define Tt 1024
#define Dd 1024
#define Hh 16

typedef __bf16 bf16x8 __attribute__((ext_vector_type(8)));
typedef __bf16 bf16x4 __attribute__((ext_vector_type(4)));
typedef float  f32x4  __attribute__((ext_vector_type(4)));

__device__ __forceinline__ void gload16(const void* g, void* l) {
    __builtin_amdgcn_global_load_lds(
        (const __attribute__((address_space(1))) void*)g,
        (__attribute__((address_space(3))) void*)l, 16, 0, 0);
}

#define VMC4() asm volatile("s_waitcnt vmcnt(4)" ::: "memory")
#define VMC0() asm volatile("s_waitcnt vmcnt(0)" ::: "memory")
#define RAWBAR() asm volatile("s_barrier" ::: "memory")

// ---------------------------------------------------------------------------
// Fused prep: [0,4096) cast x -> bf16; [4096,4864) Wqkv transpose;
// [4864,5120) Wproj transpose.  (bf16x4 transpose stores, R3)
// ---------------------------------------------------------------------------
__global__ __launch_bounds__(256) void prep(const float* __restrict__ x,
                                            const float* __restrict__ Wqkv,
                                            const float* __restrict__ Wproj,
                                            __bf16* __restrict__ xb,
                                            __bf16* __restrict__ wqT,
                                            __bf16* __restrict__ wpT) {
    const int bid = blockIdx.x;
    if (bid < 4096) {  // cast
        int i = bid * 256 + threadIdx.x;
        float4 v = ((const float4*)x)[i];
        bf16x4 o = { (__bf16)v.x, (__bf16)v.y, (__bf16)v.z, (__bf16)v.w };
        ((bf16x4*)xb)[i] = o;
        return;
    }
    __shared__ float ld[64][65];
    const float* in;
    __bf16* out;
    int K, N, k0, n0;
    if (bid < 4096 + 768) {
        int j = bid - 4096;
        in = Wqkv; out = wqT; K = 1024; N = 3072;
        k0 = (j & 15) * 64; n0 = (j >> 4) * 64;
    } else {
        int j = bid - 4096 - 768;
        in = Wproj; out = wpT; K = 1024; N = 1024;
        k0 = (j & 15) * 64; n0 = (j >> 4) * 64;
    }
    #pragma unroll
    for (int i = 0; i < 16; i++) {
        int idx = i * 256 + threadIdx.x;
        int r = idx >> 6, c = idx & 63;
        ld[r][c] = in[(size_t)(k0 + r) * N + n0 + c];
    }
    __syncthreads();
    #pragma unroll
    for (int i = 0; i < 4; i++) {
        int idx = i * 256 + threadIdx.x;      // 0..1023: r = out-row, c4 = col quad
        int r = idx >> 4, c4 = (idx & 15) * 4;
        bf16x4 o = { (__bf16)ld[c4][r], (__bf16)ld[c4 + 1][r],
                     (__bf16)ld[c4 + 2][r], (__bf16)ld[c4 + 3][r] };
        *(bf16x4*)&out[(size_t)(n0 + r) * K + k0 + c4] = o;
    }
}

// ---------------------------------------------------------------------------
// 128x128 MFMA GEMM (QKV), BK=32.  NEW (R4): TRIPLE-buffered (48 KiB LDS,
// still 3 blocks/CU) with prefetch depth 2, raw s_barrier and counted
// vmcnt(4) — removes the __syncthreads implicit vmcnt(0) drain that was
// ~60% of the kernel (both pipes measured <30% busy).  Per-wave stage = 4
// gload16; at iter-top outstanding = {t, t+1} = 8 -> vmcnt(4) forces tile t
// exactly; vmcnt(0) only on the last iter.  WAR: stage(t+2) overwrites
// buf[(t-1)%3], fully consumed before this barrier (frag reads retire
// before their MFMAs, which precede the barrier in program order).
// Epilogue unchanged EXCEPT: V-block (col0>=2048) Cout stores are DEAD
// (attn reads V only via vt) -> skipped; vt transpose kept.
// Q columns (<1024) pre-scaled by 0.125.
// ---------------------------------------------------------------------------
__global__ __launch_bounds__(256) void gemm_qkv(const __bf16* __restrict__ A,
                                                const __bf16* __restrict__ Bt,
                                                const float* __restrict__ bias,
                                                __bf16* __restrict__ Cout,
                                                __bf16* __restrict__ vt,
                                                int M, int N, int K) {
    __shared__ __align__(16) __bf16 smem[24576];  // 3 x (A 4096 | B 4096) = 48 KiB

    const int tid  = threadIdx.x;
    const int lane = tid & 63;
    const int wave = tid >> 6;
    const int wy = wave >> 1, wx = wave & 1;
    const int l15 = lane & 15, quad = lane >> 4;
    const size_t row0 = (size_t)blockIdx.y * 128;
    const size_t col0 = (size_t)blockIdx.x * 128;

    f32x4 acc[4][4] = {};

    // per-lane staging offsets (constant across tiles)
    const int c0 = tid, c1 = 256 + tid;
    const int r0 = c0 >> 2, s0 = (c0 & 3) ^ ((r0 >> 1) & 3);
    const int r1 = c1 >> 2, s1 = (c1 & 3) ^ ((r1 >> 1) & 3);

#define STAGE(it, buf) do {                                                   \
        const int _k0 = (it) << 5;                                            \
        gload16(&A[(row0 + r0) * K + _k0 + s0 * 8], &(buf)[c0 * 8]);          \
        gload16(&Bt[(col0 + r0) * K + _k0 + s0 * 8], &(buf)[4096 + c0 * 8]);  \
        gload16(&A[(row0 + r1) * K + _k0 + s1 * 8], &(buf)[c1 * 8]);          \
        gload16(&Bt[(col0 + r1) * K + _k0 + s1 * 8], &(buf)[4096 + c1 * 8]);  \
    } while (0)

    __bf16 *b0 = smem, *b1 = smem + 8192, *b2 = smem + 16384;
    STAGE(0, b0);
    STAGE(1, b1);

    const int niter = K >> 5;  // 32
    for (int it = 0; it < niter; it++) {
        if (it + 1 < niter) VMC4(); else VMC0();
        RAWBAR();
        if (it + 2 < niter) STAGE(it + 2, b2);

        bf16x8 af[4], bfr[4];
        #pragma unroll
        for (int i = 0; i < 4; i++) {
            const int r = wy * 64 + i * 16 + l15;
            af[i] = *(const bf16x8*)&b0[r * 32 + ((quad ^ ((r >> 1) & 3)) * 8)];
        }
        #pragma unroll
        for (int j = 0; j < 4; j++) {
            const int r = wx * 64 + j * 16 + l15;
            bfr[j] = *(const bf16x8*)&b0[4096 + r * 32 + ((quad ^ ((r >> 1) & 3)) * 8)];
        }
        #pragma unroll
        for (int i = 0; i < 4; i++)
            #pragma unroll
            for (int j = 0; j < 4; j++)
                acc[i][j] = __builtin_amdgcn_mfma_f32_16x16x32_bf16(af[i], bfr[j], acc[i][j], 0, 0, 0);

        __bf16* tswap = b0; b0 = b1; b1 = b2; b2 = tswap;   // rotate ring
    }
#undef STAGE

    // ---- epilogue: bias+scale -> LDS tile (stride 132) -> coalesced stores ----
    __syncthreads();
    const float scale = (col0 < 1024) ? 0.125f : 1.0f;
    #pragma unroll
    for (int j = 0; j < 4; j++) {
        const int cl = wx * 64 + j * 16 + l15;
        const float bj = bias[col0 + cl];
        #pragma unroll
        for (int i = 0; i < 4; i++) {
            const int rl = wy * 64 + i * 16 + quad * 4;
            #pragma unroll
            for (int r = 0; r < 4; r++)
                smem[(rl + r) * 132 + cl] = (__bf16)((acc[i][j][r] + bj) * scale);
        }
    }
    __syncthreads();
    if (col0 < 2048) {  // Q/K blocks: coalesced qkv stores (V's Cout is dead)
        #pragma unroll
        for (int p = 0; p < 8; p++) {
            const int row = p * 16 + (tid >> 4);
            const int ch  = tid & 15;
            bf16x8 v = *(const bf16x8*)&smem[row * 132 + ch * 8];
            *(bf16x8*)&Cout[(row0 + row) * N + col0 + ch * 8] = v;
        }
    } else {  // V block: write only vt[b][h][d][t] (t = M rows)
        const int bidx = (int)(row0 >> 10);
        const int t0g  = (int)(row0 & 1023);
        const int cl   = tid >> 1;          // tile column 0..127
        const int half = tid & 1;           // t-half 0..1
        const int hd   = (int)(col0 - 2048) + cl;
        const size_t vrow = ((size_t)((bidx * Hh + (hd >> 6)) * 64 + (hd & 63))) * Tt + t0g;
        #pragma unroll
        for (int s = 0; s < 8; s++) {
            const int t = half * 64 + s * 8;
            bf16x8 v;
            #pragma unroll
            for (int u = 0; u < 8; u++) v[u] = smem[(t + u) * 132 + cl];
            *(bf16x8*)&vt[vrow + t] = v;
        }
    }
}

// ---------------------------------------------------------------------------
// 128x64-tile GEMM (proj), BK=64, double-buffered, one barrier/iter (R3).
// ---------------------------------------------------------------------------
__global__ __launch_bounds__(256) void gemm_bf16_n64(const __bf16* __restrict__ A,
                                                     const __bf16* __restrict__ Bt,
                                                     const float* __restrict__ bias,
                                                     float* __restrict__ Cout,
                                                     int M, int N, int K) {
    __shared__ __align__(16) __bf16 As[2][128 * 64];
    __shared__ __align__(16) __bf16 Bs[2][64 * 64];
    const int tid  = threadIdx.x;
    const int lane = tid & 63;
    const int wave = tid >> 6;
    const int wy = wave >> 1, wx = wave & 1;
    const int l15 = lane & 15, quad = lane >> 4;
    const size_t row0 = (size_t)blockIdx.y * 128;
    const size_t col0 = (size_t)blockIdx.x * 64;

    f32x4 acc[4][2] = {};

    // prologue: stage tile 0
    #pragma unroll
    for (int i = 0; i < 4; i++) {
        int c = i * 256 + tid;
        int r = c >> 3, seg = (c & 7) ^ (r & 7);
        gload16(&A[(row0 + r) * K + seg * 8], &As[0][c * 8]);
    }
    #pragma unroll
    for (int i = 0; i < 2; i++) {
        int c = i * 256 + tid;
        int r = c >> 3, seg = (c & 7) ^ (r & 7);
        gload16(&Bt[(col0 + r) * K + seg * 8], &Bs[0][c * 8]);
    }

    const int niter = K >> 6;  // 16
    for (int it = 0; it < niter; ++it) {
        __syncthreads();                       // DMA(it) complete + WAR
        const int cur = it & 1;
        if (it + 1 < niter) {
            const int k0 = (it + 1) << 6;
            #pragma unroll
            for (int i = 0; i < 4; i++) {
                int c = i * 256 + tid;
                int r = c >> 3, seg = (c & 7) ^ (r & 7);
                gload16(&A[(row0 + r) * K + k0 + seg * 8], &As[cur ^ 1][c * 8]);
            }
            #pragma unroll
            for (int i = 0; i < 2; i++) {
                int c = i * 256 + tid;
                int r = c >> 3, seg = (c & 7) ^ (r & 7);
                gload16(&Bt[(col0 + r) * K + k0 + seg * 8], &Bs[cur ^ 1][c * 8]);
            }
        }
        #pragma unroll
        for (int kc = 0; kc < 2; kc++) {
            bf16x8 af[4], bfr[2];
            #pragma unroll
            for (int i = 0; i < 4; i++)
                af[i] = *(const bf16x8*)&As[cur][(wy * 64 + i * 16 + l15) * 64 +
                                                 (((kc * 4 + quad) ^ (l15 & 7)) * 8)];
            #pragma unroll
            for (int j = 0; j < 2; j++)
                bfr[j] = *(const bf16x8*)&Bs[cur][(wx * 32 + j * 16 + l15) * 64 +
                                                  (((kc * 4 + quad) ^ (l15 & 7)) * 8)];
            #pragma unroll
            for (int i = 0; i < 4; i++)
                #pragma unroll
                for (int j = 0; j < 2; j++)
                    acc[i][j] = __builtin_amdgcn_mfma_f32_16x16x32_bf16(af[i], bfr[j], acc[i][j], 0, 0, 0);
        }
    }

    #pragma unroll
    for (int j = 0; j < 2; j++) {
        const size_t col = col0 + wx * 32 + j * 16 + l15;
        const float bj = bias[col];
        #pragma unroll
        for (int i = 0; i < 4; i++) {
            const size_t row = row0 + wy * 64 + i * 16 + quad * 4;
            #pragma unroll
            for (int r = 0; r < 4; r++)
                Cout[(row + r) * N + col] = acc[i][j][r] + bj;
        }
    }
}

// ---------------------------------------------------------------------------
// Flash attention (S^T = K @ Q^T).  (unchanged)
// ---------------------------------------------------------------------------
__global__ __launch_bounds__(256, 4) void attn_mfma(const __bf16* __restrict__ qkv,
                                                    const __bf16* __restrict__ vt,
                                                    const int* __restrict__ mask,
                                                    __bf16* __restrict__ att) {
    __shared__ __align__(16) __bf16 Ks[2][4096];
    __shared__ __align__(16) __bf16 Vs[2][4096];
    __shared__ __align__(16) __bf16 Ps[4][1024];

    const int h  = blockIdx.x & 15;
    const int b  = blockIdx.x >> 4;
    const int qt = 15 - blockIdx.y;  // LPT: longest blocks dispatch first
    const int tid = threadIdx.x, lane = tid & 63, wave = tid >> 6;
    const int l15 = lane & 15, quad = lane >> 4;

    // stage Q (swizzled) through Ks[0]
    #pragma unroll
    for (int i = 0; i < 2; i++) {
        int c = i * 256 + tid;
        int rr = c >> 3, ch = c & 7;
        gload16(&qkv[((size_t)(b * Tt + qt * 64 + rr)) * 3072 + h * 64 + ((ch ^ (rr & 7)) * 8)],
                &Ks[0][c * 8]);
    }

    // mask ballot pass: tile p's 64 bits end up in lane-group (lane&15)==p
    uint32_t mlo = 0, mhi = 0;
    for (int p = 0; p < 16; p++) {
        unsigned long long bal = __ballot(mask[b * Tt + p * 64 + lane] != 0);
        if ((lane & 15) == p) { mlo = (uint32_t)bal; mhi = (uint32_t)(bal >> 32); }
    }

    __syncthreads();
    bf16x8 qf0 = *(const bf16x8*)&Ks[0][(wave * 16 + l15) * 64 + ((quad ^ (l15 & 7)) * 8)];
    bf16x8 qf1 = *(const bf16x8*)&Ks[0][(wave * 16 + l15) * 64 + (((4 + quad) ^ (l15 & 7)) * 8)];
    __syncthreads();  // Q frag reads done -> Ks[0] reusable

    #pragma unroll
    for (int i = 0; i < 2; i++) {
        int c = i * 256 + tid;
        int rr = c >> 3, ch = c & 7, sw = ((ch ^ (rr & 7)) * 8);
        gload16(&qkv[((size_t)(b * Tt + rr)) * 3072 + 1024 + h * 64 + sw], &Ks[0][c * 8]);
        gload16(&vt[((size_t)((b * Hh + h) * 64 + rr)) * Tt + sw], &Vs[0][c * 8]);
    }

    f32x4 Oacc[4] = {};
    float lsum = 0.0f;

    for (int kt = 0; kt <= qt; kt++) {
        __syncthreads();  // DMA(kt) complete (issued a full compute phase ago)
        const int cur = kt & 1;
        if (kt < qt) {
            #pragma unroll
            for (int i = 0; i < 2; i++) {
                int c = i * 256 + tid;
                int rr = c >> 3, ch = c & 7, sw = ((ch ^ (rr & 7)) * 8);
                gload16(&qkv[((size_t)(b * Tt + (kt + 1) * 64 + rr)) * 3072 + 1024 + h * 64 + sw],
                        &Ks[cur ^ 1][c * 8]);
                gload16(&vt[((size_t)((b * Hh + h) * 64 + rr)) * Tt + (kt + 1) * 64 + sw],
                        &Vs[cur ^ 1][c * 8]);
            }
        }

        // mask bits for this tile (uniform readlane, no memory access)
        const uint32_t lo = (uint32_t)__builtin_amdgcn_readlane((int)mlo, kt);
        const uint32_t hi = (uint32_t)__builtin_amdgcn_readlane((int)mhi, kt);

        bf16x8 ak[4][2];
        #pragma unroll
        for (int j = 0; j < 4; j++)
            #pragma unroll
            for (int kc = 0; kc < 2; kc++)
                ak[j][kc] = *(const bf16x8*)&Ks[cur][(j * 16 + l15) * 64 +
                                                     (((kc * 4 + quad) ^ (l15 & 7)) * 8)];
        #pragma unroll
        for (int j = 0; j < 4; j++) {
            f32x4 st = {};
            st = __builtin_amdgcn_mfma_f32_16x16x32_bf16(ak[j][0], qf0, st, 0, 0, 0);
            st = __builtin_amdgcn_mfma_f32_16x16x32_bf16(ak[j][1], qf1, st, 0, 0, 0);
            const uint32_t fld = (j < 2) ? (lo >> (j * 16)) : (hi >> ((j - 2) * 16));
            bf16x4 pv;
            #pragma unroll
            for (int r = 0; r < 4; r++) {
                const int tloc = j * 16 + quad * 4 + r;
                bool keep = (fld >> (quad * 4 + r)) & 1;
                if (kt == qt) keep = keep && (tloc <= wave * 16 + l15);
                const float pe = keep ? __expf(st[r]) : 0.0f;
                lsum += pe;
                pv[r] = (__bf16)pe;
            }
            *(bf16x4*)&Ps[wave][l15 * 64 + (((j * 4 + quad) ^ ((l15 & 7) << 1)) * 4)] = pv;
        }

        bf16x8 av[4][2];
        #pragma unroll
        for (int n = 0; n < 4; n++)
            #pragma unroll
            for (int kc = 0; kc < 2; kc++)
                av[n][kc] = *(const bf16x8*)&Vs[cur][(n * 16 + l15) * 64 +
                                                     (((kc * 4 + quad) ^ (l15 & 7)) * 8)];
        bf16x8 p0 = *(const bf16x8*)&Ps[wave][l15 * 64 + (((2 * quad) ^ ((l15 & 7) << 1)) * 4)];
        bf16x8 p1 = *(const bf16x8*)&Ps[wave][l15 * 64 + (((2 * (4 + quad)) ^ ((l15 & 7) << 1)) * 4)];
        #pragma unroll
        for (int n = 0; n < 4; n++) {
            Oacc[n] = __builtin_amdgcn_mfma_f32_16x16x32_bf16(av[n][0], p0, Oacc[n], 0, 0, 0);
            Oacc[n] = __builtin_amdgcn_mfma_f32_16x16x32_bf16(av[n][1], p1, Oacc[n], 0, 0, 0);
        }
    }

    float lt = lsum;
    lt += __shfl_xor(lt, 16);
    lt += __shfl_xor(lt, 32);
    const float inv = 1.0f / lt;
    const int q = qt * 64 + wave * 16 + l15;
    #pragma unroll
    for (int n = 0; n < 4; n++) {
        bf16x4 o;
        #pragma unroll
        for (int r = 0; r < 4; r++) o[r] = (__bf16)(Oacc[n][r] * inv);
        *(bf16x4*)&att[((size_t)(b * Tt + q)) * Dd + h * 64 + n * 16 + quad * 4] = o;
    }
}

// ---------------------------------------------------------------------------
extern "C" void kernel_launch(void* const* d_in, const int* in_sizes, int n_in,
                              void* d_out, int out_size, void* d_ws, size_t ws_size,
                              hipStream_t stream) {
    const float* x     = (const float*)d_in[0];
    const float* Wqkv  = (const float*)d_in[1];
    const float* bqkv  = (const float*)d_in[2];
    const float* Wproj = (const float*)d_in[3];
    const float* bproj = (const float*)d_in[4];
    const int*   mask  = (const int*)d_in[5];
    float* out = (float*)d_out;

    __bf16* xb  = (__bf16*)d_ws;                         // 4096*1024
    __bf16* wqT = xb  + (size_t)4096 * 1024;             // 3072*1024
    __bf16* wpT = wqT + (size_t)3072 * 1024;             // 1024*1024
    __bf16* qkv = wpT + (size_t)1024 * 1024;             // 4096*3072
    __bf16* vt  = qkv + (size_t)4096 * 3072;             // 4*16*64*1024
    __bf16* att = vt  + (size_t)4 * 16 * 64 * 1024;      // 4096*1024

    prep<<<4096 + 768 + 256, 256, 0, stream>>>(x, Wqkv, Wproj, xb, wqT, wpT);

    gemm_qkv<<<dim3(24, 32), 256, 0, stream>>>(xb, wqT, bqkv, qkv, vt, 4096, 3072, 1024);

    attn_mfma<<<dim3(64, 16), 256, 0, stream>>>(qkv, vt, mask, att);

    gemm_bf16_n64<<<dim3(16, 32), 256, 0, stream>>>(att, wpT, bproj, out, 4096, 1024, 1024);
}

// Round 5
// 157.462 us; speedup vs baseline: 1.0591x; 1.0231x over previous
//
#include <hip/hip_runtime.h>
#include <hip/hip_bf16.h>
#include <cstddef>
#include <cstdint>

#define Bb 4
#define Tt 1024
#define Dd 1024
#define Hh 16

typedef __bf16 bf16x8 __attribute__((ext_vector_type(8)));
typedef __bf16 bf16x4 __attribute__((ext_vector_type(4)));
typedef float  f32x4  __attribute__((ext_vector_type(4)));

__device__ __forceinline__ void gload16(const void* g, void* l) {
    __builtin_amdgcn_global_load_lds(
        (const __attribute__((address_space(1))) void*)g,
        (__attribute__((address_space(3))) void*)l, 16, 0, 0);
}

#define VMC6() asm volatile("s_waitcnt vmcnt(6)" ::: "memory")
#define VMC4() asm volatile("s_waitcnt vmcnt(4)" ::: "memory")
#define VMC0() asm volatile("s_waitcnt vmcnt(0)" ::: "memory")
#define RAWBAR() asm volatile("s_barrier" ::: "memory")

// ---------------------------------------------------------------------------
// Fused prep: [0,4096) cast x -> bf16; [4096,4864) Wqkv transpose;
// [4864,5120) Wproj transpose.  (bf16x4 transpose stores, R3)
// ---------------------------------------------------------------------------
__global__ __launch_bounds__(256) void prep(const float* __restrict__ x,
                                            const float* __restrict__ Wqkv,
                                            const float* __restrict__ Wproj,
                                            __bf16* __restrict__ xb,
                                            __bf16* __restrict__ wqT,
                                            __bf16* __restrict__ wpT) {
    const int bid = blockIdx.x;
    if (bid < 4096) {  // cast
        int i = bid * 256 + threadIdx.x;
        float4 v = ((const float4*)x)[i];
        bf16x4 o = { (__bf16)v.x, (__bf16)v.y, (__bf16)v.z, (__bf16)v.w };
        ((bf16x4*)xb)[i] = o;
        return;
    }
    __shared__ float ld[64][65];
    const float* in;
    __bf16* out;
    int K, N, k0, n0;
    if (bid < 4096 + 768) {
        int j = bid - 4096;
        in = Wqkv; out = wqT; K = 1024; N = 3072;
        k0 = (j & 15) * 64; n0 = (j >> 4) * 64;
    } else {
        int j = bid - 4096 - 768;
        in = Wproj; out = wpT; K = 1024; N = 1024;
        k0 = (j & 15) * 64; n0 = (j >> 4) * 64;
    }
    #pragma unroll
    for (int i = 0; i < 16; i++) {
        int idx = i * 256 + threadIdx.x;
        int r = idx >> 6, c = idx & 63;
        ld[r][c] = in[(size_t)(k0 + r) * N + n0 + c];
    }
    __syncthreads();
    #pragma unroll
    for (int i = 0; i < 4; i++) {
        int idx = i * 256 + threadIdx.x;      // 0..1023: r = out-row, c4 = col quad
        int r = idx >> 4, c4 = (idx & 15) * 4;
        bf16x4 o = { (__bf16)ld[c4][r], (__bf16)ld[c4 + 1][r],
                     (__bf16)ld[c4 + 2][r], (__bf16)ld[c4 + 3][r] };
        *(bf16x4*)&out[(size_t)(n0 + r) * K + k0 + c4] = o;
    }
}

// ---------------------------------------------------------------------------
// 128x128 MFMA GEMM (QKV), BK=32, TRIPLE-buffered (48 KiB LDS, 3 blocks/CU),
// prefetch depth 2, raw s_barrier + counted vmcnt(4).  (R4, verified)
// V-block (col0>=2048) Cout stores are dead -> only vt transpose emitted.
// Q columns (<1024) pre-scaled by 0.125.
// ---------------------------------------------------------------------------
__global__ __launch_bounds__(256) void gemm_qkv(const __bf16* __restrict__ A,
                                                const __bf16* __restrict__ Bt,
                                                const float* __restrict__ bias,
                                                __bf16* __restrict__ Cout,
                                                __bf16* __restrict__ vt,
                                                int M, int N, int K) {
    __shared__ __align__(16) __bf16 smem[24576];  // 3 x (A 4096 | B 4096) = 48 KiB

    const int tid  = threadIdx.x;
    const int lane = tid & 63;
    const int wave = tid >> 6;
    const int wy = wave >> 1, wx = wave & 1;
    const int l15 = lane & 15, quad = lane >> 4;
    const size_t row0 = (size_t)blockIdx.y * 128;
    const size_t col0 = (size_t)blockIdx.x * 128;

    f32x4 acc[4][4] = {};

    // per-lane staging offsets (constant across tiles)
    const int c0 = tid, c1 = 256 + tid;
    const int r0 = c0 >> 2, s0 = (c0 & 3) ^ ((r0 >> 1) & 3);
    const int r1 = c1 >> 2, s1 = (c1 & 3) ^ ((r1 >> 1) & 3);

#define STAGE(it, buf) do {                                                   \
        const int _k0 = (it) << 5;                                            \
        gload16(&A[(row0 + r0) * K + _k0 + s0 * 8], &(buf)[c0 * 8]);          \
        gload16(&Bt[(col0 + r0) * K + _k0 + s0 * 8], &(buf)[4096 + c0 * 8]);  \
        gload16(&A[(row0 + r1) * K + _k0 + s1 * 8], &(buf)[c1 * 8]);          \
        gload16(&Bt[(col0 + r1) * K + _k0 + s1 * 8], &(buf)[4096 + c1 * 8]);  \
    } while (0)

    __bf16 *b0 = smem, *b1 = smem + 8192, *b2 = smem + 16384;
    STAGE(0, b0);
    STAGE(1, b1);

    const int niter = K >> 5;  // 32
    for (int it = 0; it < niter; it++) {
        if (it + 1 < niter) VMC4(); else VMC0();
        RAWBAR();
        if (it + 2 < niter) STAGE(it + 2, b2);

        bf16x8 af[4], bfr[4];
        #pragma unroll
        for (int i = 0; i < 4; i++) {
            const int r = wy * 64 + i * 16 + l15;
            af[i] = *(const bf16x8*)&b0[r * 32 + ((quad ^ ((r >> 1) & 3)) * 8)];
        }
        #pragma unroll
        for (int j = 0; j < 4; j++) {
            const int r = wx * 64 + j * 16 + l15;
            bfr[j] = *(const bf16x8*)&b0[4096 + r * 32 + ((quad ^ ((r >> 1) & 3)) * 8)];
        }
        #pragma unroll
        for (int i = 0; i < 4; i++)
            #pragma unroll
            for (int j = 0; j < 4; j++)
                acc[i][j] = __builtin_amdgcn_mfma_f32_16x16x32_bf16(af[i], bfr[j], acc[i][j], 0, 0, 0);

        __bf16* tswap = b0; b0 = b1; b1 = b2; b2 = tswap;   // rotate ring
    }
#undef STAGE

    // ---- epilogue: bias+scale -> LDS tile (stride 132) -> coalesced stores ----
    __syncthreads();
    const float scale = (col0 < 1024) ? 0.125f : 1.0f;
    #pragma unroll
    for (int j = 0; j < 4; j++) {
        const int cl = wx * 64 + j * 16 + l15;
        const float bj = bias[col0 + cl];
        #pragma unroll
        for (int i = 0; i < 4; i++) {
            const int rl = wy * 64 + i * 16 + quad * 4;
            #pragma unroll
            for (int r = 0; r < 4; r++)
                smem[(rl + r) * 132 + cl] = (__bf16)((acc[i][j][r] + bj) * scale);
        }
    }
    __syncthreads();
    if (col0 < 2048) {  // Q/K blocks: coalesced qkv stores (V's Cout is dead)
        #pragma unroll
        for (int p = 0; p < 8; p++) {
            const int row = p * 16 + (tid >> 4);
            const int ch  = tid & 15;
            bf16x8 v = *(const bf16x8*)&smem[row * 132 + ch * 8];
            *(bf16x8*)&Cout[(row0 + row) * N + col0 + ch * 8] = v;
        }
    } else {  // V block: write only vt[b][h][d][t] (t = M rows)
        const int bidx = (int)(row0 >> 10);
        const int t0g  = (int)(row0 & 1023);
        const int cl   = tid >> 1;          // tile column 0..127
        const int half = tid & 1;           // t-half 0..1
        const int hd   = (int)(col0 - 2048) + cl;
        const size_t vrow = ((size_t)((bidx * Hh + (hd >> 6)) * 64 + (hd & 63))) * Tt + t0g;
        #pragma unroll
        for (int s = 0; s < 8; s++) {
            const int t = half * 64 + s * 8;
            bf16x8 v;
            #pragma unroll
            for (int u = 0; u < 8; u++) v[u] = smem[(t + u) * 132 + cl];
            *(bf16x8*)&vt[vrow + t] = v;
        }
    }
}

// ---------------------------------------------------------------------------
// 128x64-tile GEMM (proj), BK=64.  NEW (R5): qkv-R4 recipe ported — TRIPLE-
// buffered ring (3 x 24 KiB = 72 KiB LDS, grid stays 2 blocks/CU), prefetch
// depth 2, raw s_barrier + counted vmcnt(6).  The R3 form's loop-top
// __syncthreads carried an implicit vmcnt(0) that force-drained the t+1
// prefetch issued the same iteration — zero pipeline depth, serial DMA
// latency x16 iters.  Per-thread stage = 6 gload16; at iter top outstanding
// = {t, t+1} = 12 -> vmcnt(6) forces tile t exactly; vmcnt(0) last iter
// only.  WAR: stage(t+2) overwrites buf[(t-1)%3], whose ds_reads retired
// before their consuming MFMAs, which precede this barrier.
// ---------------------------------------------------------------------------
__device__ __forceinline__ void stage_proj(const __bf16* __restrict__ A,
                                           const __bf16* __restrict__ Bt,
                                           size_t row0, size_t col0, int K, int k0,
                                           __bf16* buf, int tid) {
    #pragma unroll
    for (int i = 0; i < 4; i++) {
        int c = i * 256 + tid;
        int r = c >> 3, seg = (c & 7) ^ (r & 7);
        gload16(&A[(row0 + r) * K + k0 + seg * 8], &buf[c * 8]);
    }
    #pragma unroll
    for (int i = 0; i < 2; i++) {
        int c = i * 256 + tid;
        int r = c >> 3, seg = (c & 7) ^ (r & 7);
        gload16(&Bt[(col0 + r) * K + k0 + seg * 8], &buf[8192 + c * 8]);
    }
}

__global__ __launch_bounds__(256) void gemm_bf16_n64(const __bf16* __restrict__ A,
                                                     const __bf16* __restrict__ Bt,
                                                     const float* __restrict__ bias,
                                                     float* __restrict__ Cout,
                                                     int M, int N, int K) {
    __shared__ __align__(16) __bf16 smem[36864];  // 3 x (A 8192 | B 4096) = 72 KiB
    const int tid  = threadIdx.x;
    const int lane = tid & 63;
    const int wave = tid >> 6;
    const int wy = wave >> 1, wx = wave & 1;
    const int l15 = lane & 15, quad = lane >> 4;
    const size_t row0 = (size_t)blockIdx.y * 128;
    const size_t col0 = (size_t)blockIdx.x * 64;

    f32x4 acc[4][2] = {};

    __bf16 *b0 = smem, *b1 = smem + 12288, *b2 = smem + 24576;
    stage_proj(A, Bt, row0, col0, K, 0, b0, tid);
    stage_proj(A, Bt, row0, col0, K, 64, b1, tid);

    const int niter = K >> 6;  // 16
    for (int it = 0; it < niter; ++it) {
        if (it + 1 < niter) VMC6(); else VMC0();
        RAWBAR();
        if (it + 2 < niter) stage_proj(A, Bt, row0, col0, K, (it + 2) << 6, b2, tid);

        #pragma unroll
        for (int kc = 0; kc < 2; kc++) {
            bf16x8 af[4], bfr[2];
            #pragma unroll
            for (int i = 0; i < 4; i++)
                af[i] = *(const bf16x8*)&b0[(wy * 64 + i * 16 + l15) * 64 +
                                            (((kc * 4 + quad) ^ (l15 & 7)) * 8)];
            #pragma unroll
            for (int j = 0; j < 2; j++)
                bfr[j] = *(const bf16x8*)&b0[8192 + (wx * 32 + j * 16 + l15) * 64 +
                                             (((kc * 4 + quad) ^ (l15 & 7)) * 8)];
            #pragma unroll
            for (int i = 0; i < 4; i++)
                #pragma unroll
                for (int j = 0; j < 2; j++)
                    acc[i][j] = __builtin_amdgcn_mfma_f32_16x16x32_bf16(af[i], bfr[j], acc[i][j], 0, 0, 0);
        }

        __bf16* tswap = b0; b0 = b1; b1 = b2; b2 = tswap;   // rotate ring
    }

    #pragma unroll
    for (int j = 0; j < 2; j++) {
        const size_t col = col0 + wx * 32 + j * 16 + l15;
        const float bj = bias[col];
        #pragma unroll
        for (int i = 0; i < 4; i++) {
            const size_t row = row0 + wy * 64 + i * 16 + quad * 4;
            #pragma unroll
            for (int r = 0; r < 4; r++)
                Cout[(row + r) * N + col] = acc[i][j][r] + bj;
        }
    }
}

// ---------------------------------------------------------------------------
// Flash attention (S^T = K @ Q^T).  (unchanged — its loop-top barrier drains
// only DMA(kt), which was issued a full compute phase earlier; no over-drain.)
// ---------------------------------------------------------------------------
__global__ __launch_bounds__(256, 4) void attn_mfma(const __bf16* __restrict__ qkv,
                                                    const __bf16* __restrict__ vt,
                                                    const int* __restrict__ mask,
                                                    __bf16* __restrict__ att) {
    __shared__ __align__(16) __bf16 Ks[2][4096];
    __shared__ __align__(16) __bf16 Vs[2][4096];
    __shared__ __align__(16) __bf16 Ps[4][1024];

    const int h  = blockIdx.x & 15;
    const int b  = blockIdx.x >> 4;
    const int qt = 15 - blockIdx.y;  // LPT: longest blocks dispatch first
    const int tid = threadIdx.x, lane = tid & 63, wave = tid >> 6;
    const int l15 = lane & 15, quad = lane >> 4;

    // stage Q (swizzled) through Ks[0]
    #pragma unroll
    for (int i = 0; i < 2; i++) {
        int c = i * 256 + tid;
        int rr = c >> 3, ch = c & 7;
        gload16(&qkv[((size_t)(b * Tt + qt * 64 + rr)) * 3072 + h * 64 + ((ch ^ (rr & 7)) * 8)],
                &Ks[0][c * 8]);
    }

    // mask ballot pass: tile p's 64 bits end up in lane-group (lane&15)==p
    uint32_t mlo = 0, mhi = 0;
    for (int p = 0; p < 16; p++) {
        unsigned long long bal = __ballot(mask[b * Tt + p * 64 + lane] != 0);
        if ((lane & 15) == p) { mlo = (uint32_t)bal; mhi = (uint32_t)(bal >> 32); }
    }

    __syncthreads();
    bf16x8 qf0 = *(const bf16x8*)&Ks[0][(wave * 16 + l15) * 64 + ((quad ^ (l15 & 7)) * 8)];
    bf16x8 qf1 = *(const bf16x8*)&Ks[0][(wave * 16 + l15) * 64 + (((4 + quad) ^ (l15 & 7)) * 8)];
    __syncthreads();  // Q frag reads done -> Ks[0] reusable

    #pragma unroll
    for (int i = 0; i < 2; i++) {
        int c = i * 256 + tid;
        int rr = c >> 3, ch = c & 7, sw = ((ch ^ (rr & 7)) * 8);
        gload16(&qkv[((size_t)(b * Tt + rr)) * 3072 + 1024 + h * 64 + sw], &Ks[0][c * 8]);
        gload16(&vt[((size_t)((b * Hh + h) * 64 + rr)) * Tt + sw], &Vs[0][c * 8]);
    }

    f32x4 Oacc[4] = {};
    float lsum = 0.0f;

    for (int kt = 0; kt <= qt; kt++) {
        __syncthreads();  // DMA(kt) complete (issued a full compute phase ago)
        const int cur = kt & 1;
        if (kt < qt) {
            #pragma unroll
            for (int i = 0; i < 2; i++) {
                int c = i * 256 + tid;
                int rr = c >> 3, ch = c & 7, sw = ((ch ^ (rr & 7)) * 8);
                gload16(&qkv[((size_t)(b * Tt + (kt + 1) * 64 + rr)) * 3072 + 1024 + h * 64 + sw],
                        &Ks[cur ^ 1][c * 8]);
                gload16(&vt[((size_t)((b * Hh + h) * 64 + rr)) * Tt + (kt + 1) * 64 + sw],
                        &Vs[cur ^ 1][c * 8]);
            }
        }

        // mask bits for this tile (uniform readlane, no memory access)
        const uint32_t lo = (uint32_t)__builtin_amdgcn_readlane((int)mlo, kt);
        const uint32_t hi = (uint32_t)__builtin_amdgcn_readlane((int)mhi, kt);

        bf16x8 ak[4][2];
        #pragma unroll
        for (int j = 0; j < 4; j++)
            #pragma unroll
            for (int kc = 0; kc < 2; kc++)
                ak[j][kc] = *(const bf16x8*)&Ks[cur][(j * 16 + l15) * 64 +
                                                     (((kc * 4 + quad) ^ (l15 & 7)) * 8)];
        #pragma unroll
        for (int j = 0; j < 4; j++) {
            f32x4 st = {};
            st = __builtin_amdgcn_mfma_f32_16x16x32_bf16(ak[j][0], qf0, st, 0, 0, 0);
            st = __builtin_amdgcn_mfma_f32_16x16x32_bf16(ak[j][1], qf1, st, 0, 0, 0);
            const uint32_t fld = (j < 2) ? (lo >> (j * 16)) : (hi >> ((j - 2) * 16));
            bf16x4 pv;
            #pragma unroll
            for (int r = 0; r < 4; r++) {
                const int tloc = j * 16 + quad * 4 + r;
                bool keep = (fld >> (quad * 4 + r)) & 1;
                if (kt == qt) keep = keep && (tloc <= wave * 16 + l15);
                const float pe = keep ? __expf(st[r]) : 0.0f;
                lsum += pe;
                pv[r] = (__bf16)pe;
            }
            *(bf16x4*)&Ps[wave][l15 * 64 + (((j * 4 + quad) ^ ((l15 & 7) << 1)) * 4)] = pv;
        }

        bf16x8 av[4][2];
        #pragma unroll
        for (int n = 0; n < 4; n++)
            #pragma unroll
            for (int kc = 0; kc < 2; kc++)
                av[n][kc] = *(const bf16x8*)&Vs[cur][(n * 16 + l15) * 64 +
                                                     (((kc * 4 + quad) ^ (l15 & 7)) * 8)];
        bf16x8 p0 = *(const bf16x8*)&Ps[wave][l15 * 64 + (((2 * quad) ^ ((l15 & 7) << 1)) * 4)];
        bf16x8 p1 = *(const bf16x8*)&Ps[wave][l15 * 64 + (((2 * (4 + quad)) ^ ((l15 & 7) << 1)) * 4)];
        #pragma unroll
        for (int n = 0; n < 4; n++) {
            Oacc[n] = __builtin_amdgcn_mfma_f32_16x16x32_bf16(av[n][0], p0, Oacc[n], 0, 0, 0);
            Oacc[n] = __builtin_amdgcn_mfma_f32_16x16x32_bf16(av[n][1], p1, Oacc[n], 0, 0, 0);
        }
    }

    float lt = lsum;
    lt += __shfl_xor(lt, 16);
    lt += __shfl_xor(lt, 32);
    const float inv = 1.0f / lt;
    const int q = qt * 64 + wave * 16 + l15;
    #pragma unroll
    for (int n = 0; n < 4; n++) {
        bf16x4 o;
        #pragma unroll
        for (int r = 0; r < 4; r++) o[r] = (__bf16)(Oacc[n][r] * inv);
        *(bf16x4*)&att[((size_t)(b * Tt + q)) * Dd + h * 64 + n * 16 + quad * 4] = o;
    }
}

// ---------------------------------------------------------------------------
extern "C" void kernel_launch(void* const* d_in, const int* in_sizes, int n_in,
                              void* d_out, int out_size, void* d_ws, size_t ws_size,
                              hipStream_t stream) {
    const float* x     = (const float*)d_in[0];
    const float* Wqkv  = (const float*)d_in[1];
    const float* bqkv  = (const float*)d_in[2];
    const float* Wproj = (const float*)d_in[3];
    const float* bproj = (const float*)d_in[4];
    const int*   mask  = (const int*)d_in[5];
    float* out = (float*)d_out;

    __bf16* xb  = (__bf16*)d_ws;                         // 4096*1024
    __bf16* wqT = xb  + (size_t)4096 * 1024;             // 3072*1024
    __bf16* wpT = wqT + (size_t)3072 * 1024;             // 1024*1024
    __bf16* qkv = wpT + (size_t)1024 * 1024;             // 4096*3072
    __bf16* vt  = qkv + (size_t)4096 * 3072;             // 4*16*64*1024
    __bf16* att = vt  + (size_t)4 * 16 * 64 * 1024;      // 4096*1024

    prep<<<4096 + 768 + 256, 256, 0, stream>>>(x, Wqkv, Wproj, xb, wqT, wpT);

    gemm_qkv<<<dim3(24, 32), 256, 0, stream>>>(xb, wqT, bqkv, qkv, vt, 4096, 3072, 1024);

    attn_mfma<<<dim3(64, 16), 256, 0, stream>>>(qkv, vt, mask, att);

    gemm_bf16_n64<<<dim3(16, 32), 256, 0, stream>>>(att, wpT, bproj, out, 4096, 1024, 1024);
}